// Round 1
// baseline (630.527 us; speedup 1.0000x reference)
//
#include <hip/hip_runtime.h>
#include <hip/hip_bf16.h>
#include <math.h>

// Transformer block, MI355X gfx950.
// R6: GEMM rewritten as 256-wide-tile counted-vmcnt deep pipeline:
//   BK=32, 4-slot LDS rotation (prefetch 3 K-tiles ahead, ~900cy cover),
//   one raw s_barrier + one counted s_waitcnt vmcnt(N) per K-step (never
//   drains to 0 in steady state), 512 thr / 8 waves (2Mx4N), chunk-XOR
//   LDS swizzle retained, s_setprio(1) around MFMA cluster.
//   BM=256 for QKV/FF1; BM=128 for proj/FF2 (N=1024 -> 256 blocks = all CUs).
// Attention unchanged from R4 (operand-swapped, reg-resident P).

typedef __bf16 bf16_t;
typedef __bf16 bf16x8 __attribute__((ext_vector_type(8)));
typedef __bf16 bf16x4 __attribute__((ext_vector_type(4)));
typedef float f32x4 __attribute__((ext_vector_type(4)));
typedef float f32x16 __attribute__((ext_vector_type(16)));

#define HID   1024
#define NHEAD 16
#define HD    64
#define EXPD  4096
#define LSEQ  2048
#define BATCH 4
#define MROWS (BATCH * LSEQ)   // 8192

#if __has_builtin(__builtin_amdgcn_exp2f)
#define EXP2F __builtin_amdgcn_exp2f
#else
#define EXP2F exp2f
#endif

__device__ __forceinline__ void gld_lds16(const bf16_t* g, bf16_t* l) {
  __builtin_amdgcn_global_load_lds(
      (const __attribute__((address_space(1))) void*)g,
      (__attribute__((address_space(3))) void*)l, 16, 0, 0);
}

template <int N>
__device__ __forceinline__ void wait_vm() {
  if constexpr (N == 8)      asm volatile("s_waitcnt vmcnt(8)" ::: "memory");
  else if constexpr (N == 6) asm volatile("s_waitcnt vmcnt(6)" ::: "memory");
  else if constexpr (N == 4) asm volatile("s_waitcnt vmcnt(4)" ::: "memory");
  else if constexpr (N == 3) asm volatile("s_waitcnt vmcnt(3)" ::: "memory");
  else                       asm volatile("s_waitcnt vmcnt(0)" ::: "memory");
}

// a'[0:31]=a, a'[32:63]=b[0:31]; b'[0:31]=a[32:63], b'[32:63]=b
__device__ __forceinline__ void swap32(unsigned& a, unsigned& b) {
#if __has_builtin(__builtin_amdgcn_permlane32_swap)
  auto r = __builtin_amdgcn_permlane32_swap(a, b, false, false);
  a = r[0]; b = r[1];
#else
  bool hiL = ((threadIdx.x & 63) >= 32);
  unsigned pa = (unsigned)__shfl_xor((int)a, 32, 64);
  unsigned pb = (unsigned)__shfl_xor((int)b, 32, 64);
  unsigned na = hiL ? pb : a;
  unsigned nb = hiL ? b : pa;
  a = na; b = nb;
#endif
}

__device__ __forceinline__ unsigned pk_bf16(float lo, float hi) {
  bf16_t l = (bf16_t)lo, h = (bf16_t)hi;
  unsigned short ul, uh;
  __builtin_memcpy(&ul, &l, 2);
  __builtin_memcpy(&uh, &h, 2);
  return (unsigned)ul | ((unsigned)uh << 16);
}

// ---------------- convert f32 -> bf16 (x) ----------------
__global__ __launch_bounds__(256) void cvt_bf16(const float* __restrict__ in,
                                                bf16_t* __restrict__ out, int n4) {
  int i = blockIdx.x * 256 + threadIdx.x;
  if (i >= n4) return;
  float4 v = ((const float4*)in)[i];
  bf16x4 o;
  o[0] = (bf16_t)v.x; o[1] = (bf16_t)v.y; o[2] = (bf16_t)v.z; o[3] = (bf16_t)v.w;
  ((bf16x4*)out)[i] = o;
}

// ---------------- transpose + convert: W[K][N] f32 -> Wt[N][K] bf16 ----------------
__global__ __launch_bounds__(256) void transpose_cvt(const float* __restrict__ W,
                                                     bf16_t* __restrict__ Wt,
                                                     int K, int N) {
  __shared__ float tile[32][33];
  int n0 = blockIdx.x * 32, k0 = blockIdx.y * 32;
  int tx = threadIdx.x & 31, ty = threadIdx.x >> 5;
#pragma unroll
  for (int i = 0; i < 32; i += 8)
    tile[ty + i][tx] = W[(size_t)(k0 + ty + i) * N + n0 + tx];
  __syncthreads();
#pragma unroll
  for (int i = 0; i < 32; i += 8)
    Wt[(size_t)(n0 + ty + i) * K + k0 + tx] = (bf16_t)tile[tx][ty + i];
}

// ---------------- transpose V: qkvb V-part -> vT[b*16+h][d][l] bf16 ----------------
__global__ __launch_bounds__(256) void transpose_v(const bf16_t* __restrict__ qkvb,
                                                   bf16_t* __restrict__ vT) {
  __shared__ bf16_t tile[64][65];
  const int l0 = blockIdx.x * 64;
  const int bh = blockIdx.y;
  const int b = bh >> 4, h = bh & 15;
  const int tx = threadIdx.x & 63, ty = threadIdx.x >> 6;
  const bf16_t* src = qkvb + ((size_t)(b * LSEQ + l0)) * 3072 + 2048 + h * 64;
#pragma unroll
  for (int i = 0; i < 16; ++i) {
    int l = ty + 4 * i;
    tile[l][tx] = src[(size_t)l * 3072 + tx];
  }
  __syncthreads();
  bf16_t* dst = vT + ((size_t)bh * HD) * LSEQ + l0;
#pragma unroll
  for (int i = 0; i < 16; ++i) {
    int d = ty + 4 * i;
    dst[(size_t)d * LSEQ + tx] = tile[tx][d];
  }
}

// ---------------- GEMM: C[M][N] = A[M][K] @ Bt[N][K]^T + bias ----------------
// mode 0: bf16 out; mode 1: gelu(tanh) then bf16 out; mode 2: f32 out.
// BN = 256 fixed, BM template (256 or 128). BK = 32.
// Deep pipeline: 4 LDS slots per operand, stage tile kt+3 while computing kt.
// One raw s_barrier + counted vmcnt per K-step (never vmcnt(0) in steady state).
// Requires K >= 128 (NT >= 4).
template <int BM>
__global__ __launch_bounds__(512, 2) void gemm_p(const bf16_t* __restrict__ A,
                                                 const bf16_t* __restrict__ Bt,
                                                 const float* __restrict__ bias,
                                                 void* __restrict__ C,
                                                 int M, int N, int K, int mode) {
  constexpr int MI = BM / 32;               // A frags per wave (M dir)
  constexpr int LOADS = (BM == 256) ? 4 : 3;  // per-thread gld_lds per K-tile
  __shared__ bf16_t As[4 * BM * 32];
  __shared__ bf16_t Bs[4 * 256 * 32];

  // group-M block swizzle: same-XCD blocks (ids = c mod 8) share an A-strip
  const int nbx = gridDim.x;
  int p = blockIdx.y * nbx + blockIdx.x;
  const int GM = 8;
  int group = p / (GM * nbx);
  int idx = p - group * (GM * nbx);
  const int by = group * GM + (idx & (GM - 1));
  const int bx = idx >> 3;  // GM == 8
  const int n0 = bx * 256, m0 = by * BM;

  const int t = threadIdx.x;
  const int lane = t & 63, w = t >> 6;
  const int wr = w >> 2, wc = w & 3;       // 2 x 4 wave grid
  const int quad = lane >> 4, l16 = lane & 15;

  f32x4 acc[MI][4];
#pragma unroll
  for (int i = 0; i < MI; ++i)
#pragma unroll
    for (int j = 0; j < 4; ++j) acc[i][j] = (f32x4){0.f, 0.f, 0.f, 0.f};

  // loop-invariant per-lane DMA source offsets (chunk-XOR swizzled k-chunk)
  const int r0 = t >> 2;                                       // 0..127
  const unsigned ksw = (((unsigned)t & 3u) ^ ((unsigned)(r0 >> 1) & 3u)) * 8u;
  const unsigned offR0 = (unsigned)r0 * (unsigned)K + ksw;
  const unsigned off128 = offR0 + 128u * (unsigned)K;  // (r+128)>>1 &3 == (r>>1)&3

  const bf16_t* aB = A + (size_t)m0 * K;
  const bf16_t* bB = Bt + (size_t)n0 * K;

  // loop-invariant LDS frag read offsets (elems); pos = quad ^ ((row>>1)&3)
  unsigned aoff[MI], boff[4];
#pragma unroll
  for (int i = 0; i < MI; ++i) {
    int row = wr * (BM / 2) + 16 * i + l16;
    aoff[i] = (unsigned)(row * 32 + (quad ^ ((row >> 1) & 3)) * 8);
  }
#pragma unroll
  for (int j = 0; j < 4; ++j) {
    int row = wc * 64 + 16 * j + l16;
    boff[j] = (unsigned)(row * 32 + (quad ^ ((row >> 1) & 3)) * 8);
  }

  auto stage = [&](int slot, int kk) {
    bf16_t* Asl = As + slot * (BM * 32);
    bf16_t* Bsl = Bs + slot * (256 * 32);
    const bf16_t* aS = aB + kk;
    const bf16_t* bS = bB + kk;
    gld_lds16(aS + offR0, Asl + t * 8);
    if constexpr (BM == 256) gld_lds16(aS + off128, Asl + (t + 512) * 8);
    gld_lds16(bS + offR0, Bsl + t * 8);
    gld_lds16(bS + off128, Bsl + (t + 512) * 8);
  };

  auto compute = [&](int slot) {
    const bf16_t* Asl = As + slot * (BM * 32);
    const bf16_t* Bsl = Bs + slot * (256 * 32);
    bf16x8 af[MI], bfr[4];
#pragma unroll
    for (int i = 0; i < MI; ++i) af[i] = *(const bf16x8*)(Asl + aoff[i]);
#pragma unroll
    for (int j = 0; j < 4; ++j) bfr[j] = *(const bf16x8*)(Bsl + boff[j]);
    __builtin_amdgcn_s_setprio(1);
#pragma unroll
    for (int i = 0; i < MI; ++i)
#pragma unroll
      for (int j = 0; j < 4; ++j)
        acc[i][j] = __builtin_amdgcn_mfma_f32_16x16x32_bf16(af[i], bfr[j], acc[i][j], 0, 0, 0);
    __builtin_amdgcn_s_setprio(0);
  };

  const int NT = K >> 5;   // K/32 tiles; NT >= 4 required

  // prologue: stage tiles 0..2
  stage(0, 0);
  stage(1, 32);
  stage(2, 64);
  int kk = 96;

  int kt = 0;
  for (; kt < NT - 3; ++kt) {
    wait_vm<2 * LOADS>();               // tile kt landed (kt+1,kt+2 in flight)
    __builtin_amdgcn_s_barrier();       // all waves' kt loads visible; slot kt+3 free
    asm volatile("" ::: "memory");
    stage((kt + 3) & 3, kk);            // issue next prefetch first (hides HBM)
    kk += 32;
    compute(kt & 3);
  }
  // tail: kt = NT-3, NT-2, NT-1 (no more staging)
  wait_vm<2 * LOADS>();
  __builtin_amdgcn_s_barrier();
  asm volatile("" ::: "memory");
  compute(kt & 3);
  ++kt;
  wait_vm<LOADS>();
  __builtin_amdgcn_s_barrier();
  asm volatile("" ::: "memory");
  compute(kt & 3);
  ++kt;
  wait_vm<0>();
  __builtin_amdgcn_s_barrier();
  asm volatile("" ::: "memory");
  compute(kt & 3);

#pragma unroll
  for (int i = 0; i < MI; ++i) {
    int rowb = m0 + wr * (BM / 2) + 16 * i + quad * 4;
#pragma unroll
    for (int j = 0; j < 4; ++j) {
      int col = n0 + wc * 64 + 16 * j + l16;
      float bv = bias[col];
#pragma unroll
      for (int r = 0; r < 4; ++r) {
        float v = acc[i][j][r] + bv;
        size_t idx = (size_t)(rowb + r) * N + col;
        if (mode == 0) {
          ((bf16_t*)C)[idx] = (bf16_t)v;
        } else if (mode == 1) {
          // tanh-approx gelu (max |err| ~3e-4, threshold 0.109)
          float u = v * (0.7978845608028654f + 0.0356774081f * v * v);
          float e = EXP2F(u * 2.885390082f);  // exp(2u) = 2^(2u*log2e)
          float th = (e - 1.f) / (e + 1.f);
          float gel = 0.5f * v * (1.f + th);
          ((bf16_t*)C)[idx] = (bf16_t)gel;
        } else {
          ((float*)C)[idx] = v;
        }
      }
    }
  }
}

// ---------------- flash attention: 128q/block, operand-swapped, reg-resident P ----------------
// S^T[k][q] = K·(sc·Q)^T  (A=K, B=Q) ; O^T[d][q] = V^T · P^T  (A=V^T, B=P^T in regs)
__global__ __launch_bounds__(256) void attn_kernel(const bf16_t* __restrict__ qkv,
                                                   const bf16_t* __restrict__ vT,
                                                   bf16_t* __restrict__ ob) {
  __shared__ bf16_t smem[3 * 128 * 64];   // 48 KB: Ks | Vts | Qs
  bf16_t* Ks  = smem;           // [128 k][64 d]  unpadded, chunk-XOR swizzle
  bf16_t* Vts = smem + 8192;    // [64 d][128 j]  unpadded, chunk-XOR swizzle
  bf16_t* Qs  = smem + 16384;   // [128 q][64 d]  unpadded, chunk-XOR swizzle
  const int qt = blockIdx.x, h = blockIdx.y, b = blockIdx.z;
  const int t = threadIdx.x, lane = t & 63, w = t >> 6;
  const int l32 = lane & 31, hi = lane >> 5;
  const size_t RS = 3 * HID;
  const int bh = b * NHEAD + h;

  const bf16_t* qbase = qkv + ((size_t)(b * LSEQ + qt * 128)) * RS + h * HD;
  const bf16_t* kbase = qkv + ((size_t)b * LSEQ) * RS + HID + h * HD;
  const bf16_t* vtbase = vT + (size_t)bh * HD * LSEQ;

  // stage Q [128][64] via DMA, source-swizzled
#pragma unroll
  for (int s = 0; s < 4; ++s) {
    int l = t + s * 256;
    int r = l >> 3, c8 = l & 7;
    gld_lds16(qbase + (size_t)r * RS + ((c8 ^ (r & 7)) * 8), Qs + l * 8);
  }
  __syncthreads();

  // hoist Q B-frags (wave w owns q-tile 32w), pre-scaled
  const float sc = 0.18033688011112042f;  // (1/sqrt(64)) * log2(e)
  bf16x8 bq[4];
  {
    int qrow = 32 * w + l32;
#pragma unroll
    for (int c = 0; c < 4; ++c) {
      int y = 2 * c + hi;
      bf16x8 q8 = *(const bf16x8*)(Qs + qrow * 64 + ((y ^ (qrow & 7)) * 8));
#pragma unroll
      for (int e = 0; e < 8; ++e) q8[e] = (bf16_t)((float)q8[e] * sc);
      bq[c] = q8;
    }
  }

  f32x16 accO[2];
#pragma unroll
  for (int dt = 0; dt < 2; ++dt)
#pragma unroll
    for (int e = 0; e < 16; ++e) accO[dt][e] = 0.f;
  float l_acc = 0.f;

  for (int kt = 0; kt < LSEQ / 128; ++kt) {
    __syncthreads();  // prior reads done (iter 0: Q hoist done)
#pragma unroll
    for (int s = 0; s < 4; ++s) {
      int l = t + s * 256;
      int r = l >> 3, c8 = l & 7;
      gld_lds16(kbase + (size_t)(kt * 128 + r) * RS + ((c8 ^ (r & 7)) * 8), Ks + l * 8);
      int rv = l >> 4, c16 = l & 15;
      gld_lds16(vtbase + (size_t)rv * LSEQ + kt * 128 + ((c16 ^ (rv & 7)) * 8), Vts + l * 8);
    }
    __syncthreads();

#pragma unroll
    for (int kt2 = 0; kt2 < 2; ++kt2) {
      // S^T for 2 k-tiles (rows 64*kt2 .. +64) x this wave's 32 q
      f32x16 s0, s1;
#pragma unroll
      for (int e = 0; e < 16; ++e) { s0[e] = 0.f; s1[e] = 0.f; }
#pragma unroll
      for (int c = 0; c < 4; ++c) {
        int y = 2 * c + hi;
        int r0 = (2 * kt2 + 0) * 32 + l32;
        bf16x8 a0 = *(const bf16x8*)(Ks + r0 * 64 + ((y ^ (r0 & 7)) * 8));
        s0 = __builtin_amdgcn_mfma_f32_32x32x16_bf16(a0, bq[c], s0, 0, 0, 0);
        int r1 = (2 * kt2 + 1) * 32 + l32;
        bf16x8 a1 = *(const bf16x8*)(Ks + r1 * 64 + ((y ^ (r1 & 7)) * 8));
        s1 = __builtin_amdgcn_mfma_f32_32x32x16_bf16(a1, bq[c], s1, 0, 0, 0);
      }

      // p = exp2(s); pack to bf16 pairs; assemble P^T B-frags via permlane swaps
      unsigned pf[2][2][4];  // [tile][c2][reg]
#pragma unroll
      for (int tile = 0; tile < 2; ++tile) {
        f32x16& sv = tile ? s1 : s0;
        float p[16];
#pragma unroll
        for (int e = 0; e < 16; ++e) { p[e] = EXP2F(sv[e]); l_acc += p[e]; }
        unsigned lo[4], hi_[4];
#pragma unroll
        for (int g = 0; g < 4; ++g) {
          lo[g] = pk_bf16(p[4 * g + 0], p[4 * g + 1]);
          hi_[g] = pk_bf16(p[4 * g + 2], p[4 * g + 3]);
        }
#pragma unroll
        for (int c2 = 0; c2 < 2; ++c2) {
          unsigned aL = lo[2 * c2], bL = lo[2 * c2 + 1];
          swap32(aL, bL);
          pf[tile][c2][0] = aL; pf[tile][c2][2] = bL;
          unsigned aH = hi_[2 * c2], bH = hi_[2 * c2 + 1];
          swap32(aH, bH);
          pf[tile][c2][1] = aH; pf[tile][c2][3] = bH;
        }
      }

      // O^T += V^T · P^T
#pragma unroll
      for (int dt = 0; dt < 2; ++dt)
#pragma unroll
        for (int tile = 0; tile < 2; ++tile)
#pragma unroll
          for (int c2 = 0; c2 < 2; ++c2) {
            int ktile = 2 * kt2 + tile;
            int c8v = ktile * 4 + c2 * 2 + hi;
            int rv = dt * 32 + l32;
            bf16x8 av = *(const bf16x8*)(Vts + rv * 128 + ((c8v ^ (rv & 7)) * 8));
            union { unsigned u[4]; bf16x8 v; } bp;
            bp.u[0] = pf[tile][c2][0]; bp.u[1] = pf[tile][c2][1];
            bp.u[2] = pf[tile][c2][2]; bp.u[3] = pf[tile][c2][3];
            accO[dt] = __builtin_amdgcn_mfma_f32_32x32x16_bf16(av, bp.v, accO[dt], 0, 0, 0);
          }
    }
  }

  // denominator: col q = l32 per lane; halves hold partial sums
  l_acc += __shfl_xor(l_acc, 32, 64);
  float inv = 1.f / l_acc;

  // epilogue: O^T -> LDS (stride 68) -> coalesced global
  __syncthreads();
  bf16_t* Osh = smem;
  {
    int q = 32 * w + l32;
#pragma unroll
    for (int dt = 0; dt < 2; ++dt)
#pragma unroll
      for (int e = 0; e < 16; ++e) {
        int d = dt * 32 + (e & 3) + 8 * (e >> 2) + 4 * hi;
        Osh[q * 68 + d] = (bf16_t)(accO[dt][e] * inv);
      }
  }
  __syncthreads();
#pragma unroll
  for (int s = 0; s < 4; ++s) {
    int l = t + s * 256;
    int r = l >> 3, c8 = l & 7;
    bf16x8 v = *(const bf16x8*)(Osh + r * 68 + c8 * 8);
    *(bf16x8*)(ob + ((size_t)(b * LSEQ + qt * 128 + r)) * HID + h * HD + c8 * 8) = v;
  }
}

// ---------------- residual add + LayerNorm ----------------
__global__ __launch_bounds__(256) void resid_ln(const float* __restrict__ X,
                                                const float* __restrict__ Y,
                                                const float* __restrict__ g,
                                                const float* __restrict__ be,
                                                float* __restrict__ outf,
                                                bf16_t* __restrict__ outb) {
  const int row = blockIdx.x;
  const int t = threadIdx.x;
  float4 a = ((const float4*)X)[(size_t)row * 256 + t];
  float4 bvec = ((const float4*)Y)[(size_t)row * 256 + t];
  float v0 = a.x + bvec.x, v1 = a.y + bvec.y, v2 = a.z + bvec.z, v3 = a.w + bvec.w;
  float s = v0 + v1 + v2 + v3;
  float s2 = v0 * v0 + v1 * v1 + v2 * v2 + v3 * v3;
#pragma unroll
  for (int msk = 1; msk < 64; msk <<= 1) {
    s += __shfl_xor(s, msk, 64);
    s2 += __shfl_xor(s2, msk, 64);
  }
  __shared__ float red[8];
  int w = t >> 6;
  if ((t & 63) == 0) { red[w] = s; red[w + 4] = s2; }
  __syncthreads();
  s = red[0] + red[1] + red[2] + red[3];
  s2 = red[4] + red[5] + red[6] + red[7];
  float mu = s * (1.f / 1024.f);
  float var = s2 * (1.f / 1024.f) - mu * mu;
  float rstd = rsqrtf(var + 1e-5f);
  float4 gg = ((const float4*)g)[t];
  float4 bb = ((const float4*)be)[t];
  float o0 = (v0 - mu) * rstd * gg.x + bb.x;
  float o1 = (v1 - mu) * rstd * gg.y + bb.y;
  float o2 = (v2 - mu) * rstd * gg.z + bb.z;
  float o3 = (v3 - mu) * rstd * gg.w + bb.w;
  float4 o = {o0, o1, o2, o3};
  ((float4*)outf)[(size_t)row * 256 + t] = o;
  if (outb) {
    bf16x4 ob4;
    ob4[0] = (bf16_t)o0; ob4[1] = (bf16_t)o1; ob4[2] = (bf16_t)o2; ob4[3] = (bf16_t)o3;
    ((bf16x4*)outb)[(size_t)row * 256 + t] = ob4;
  }
}

// ---------------- host ----------------
extern "C" void kernel_launch(void* const* d_in, const int* in_sizes, int n_in,
                              void* d_out, int out_size, void* d_ws, size_t ws_size,
                              hipStream_t stream) {
  const float* x     = (const float*)d_in[0];
  const float* Wqkv  = (const float*)d_in[1];
  const float* bqkv  = (const float*)d_in[2];
  const float* Wproj = (const float*)d_in[3];
  const float* bproj = (const float*)d_in[4];
  const float* W1    = (const float*)d_in[5];
  const float* b1    = (const float*)d_in[6];
  const float* W2    = (const float*)d_in[7];
  const float* b2    = (const float*)d_in[8];
  const float* g1    = (const float*)d_in[9];
  const float* be1   = (const float*)d_in[10];
  const float* g2    = (const float*)d_in[11];
  const float* be2   = (const float*)d_in[12];
  float* out = (float*)d_out;

  char* ws = (char*)d_ws;
  size_t off = 0;
  auto alloc = [&](size_t bytes) -> char* {
    char* p = ws + off;
    off += (bytes + 255) & ~(size_t)255;
    return p;
  };
  bf16_t* wqkvT  = (bf16_t*)alloc((size_t)3072 * 1024 * 2);
  bf16_t* wprojT = (bf16_t*)alloc((size_t)1024 * 1024 * 2);
  bf16_t* w1T    = (bf16_t*)alloc((size_t)4096 * 1024 * 2);
  bf16_t* w2T    = (bf16_t*)alloc((size_t)1024 * 4096 * 2);
  char*   xb_ob  = alloc((size_t)MROWS * HID * 2);
  char*   qkv_ff = alloc((size_t)MROWS * EXPD * 2);
  char*   a_f2   = alloc((size_t)MROWS * HID * 4);
  float*  h      = (float*)alloc((size_t)MROWS * HID * 4);
  bf16_t* hb     = (bf16_t*)alloc((size_t)MROWS * HID * 2);

  bf16_t* xb    = (bf16_t*)xb_ob;
  bf16_t* ob    = (bf16_t*)xb_ob;
  bf16_t* qkvb  = (bf16_t*)qkv_ff;
  bf16_t* ff1b  = (bf16_t*)qkv_ff;
  float*  attnf = (float*)a_f2;
  float*  ff2f  = (float*)a_f2;
  bf16_t* vTg   = hb;  // alias: vT live only qkv->attn; hb live only after LN1

  dim3 blk(256);
  dim3 blk512(512);
  transpose_cvt<<<dim3(3072 / 32, 1024 / 32), blk, 0, stream>>>(Wqkv, wqkvT, 1024, 3072);
  transpose_cvt<<<dim3(1024 / 32, 1024 / 32), blk, 0, stream>>>(Wproj, wprojT, 1024, 1024);
  transpose_cvt<<<dim3(4096 / 32, 1024 / 32), blk, 0, stream>>>(W1, w1T, 1024, 4096);
  transpose_cvt<<<dim3(1024 / 32, 4096 / 32), blk, 0, stream>>>(W2, w2T, 4096, 1024);
  cvt_bf16<<<MROWS * HID / 4 / 256, blk, 0, stream>>>(x, xb, MROWS * HID / 4);

  gemm_p<256><<<dim3(3072 / 256, MROWS / 256), blk512, 0, stream>>>(xb, wqkvT, bqkv, qkvb,
                                                                    MROWS, 3072, 1024, 0);
  transpose_v<<<dim3(LSEQ / 64, BATCH * NHEAD), blk, 0, stream>>>(qkvb, vTg);
  attn_kernel<<<dim3(LSEQ / 128, NHEAD, BATCH), blk, 0, stream>>>(qkvb, vTg, ob);
  gemm_p<128><<<dim3(1024 / 256, MROWS / 128), blk512, 0, stream>>>(ob, wprojT, bproj, attnf,
                                                                    MROWS, 1024, 1024, 2);
  resid_ln<<<MROWS, blk, 0, stream>>>(x, attnf, g1, be1, h, hb);
  gemm_p<256><<<dim3(4096 / 256, MROWS / 256), blk512, 0, stream>>>(hb, w1T, b1, ff1b,
                                                                    MROWS, 4096, 1024, 1);
  gemm_p<128><<<dim3(1024 / 256, MROWS / 128), blk512, 0, stream>>>(ff1b, w2T, b2, ff2f,
                                                                    MROWS, 1024, 4096, 2);
  resid_ln<<<MROWS, blk, 0, stream>>>(h, ff2f, g2, be2, out, (bf16_t*)nullptr);
}

// Round 2
// 626.486 us; speedup vs baseline: 1.0065x; 1.0065x over previous
//
#include <hip/hip_runtime.h>
#include <hip/hip_bf16.h>
#include <math.h>

// Transformer block, MI355X gfx950.
// R7: GEMM = fine-grained 2-phase-per-K-step schedule (m201-style) on the
//   R6 4-slot BK=32 rotation: per phase {8/4 ds_read_b128 + 2 gld_lds ->
//   s_barrier -> lgkmcnt(0) -> setprio(1) 16xMFMA setprio(0) -> s_barrier},
//   counted vmcnt(2*LOADS) once per K-step placed BEFORE the phase-1
//   barrier (barrier publishes tile-landed block-wide; never vmcnt(0) in
//   steady state). BM=256; BN=256 for QKV/FF1, BN=128 for proj/FF2
//   (grid 256 blocks = 1 full round).
// Attention unchanged from R4 (operand-swapped, reg-resident P).

typedef __bf16 bf16_t;
typedef __bf16 bf16x8 __attribute__((ext_vector_type(8)));
typedef __bf16 bf16x4 __attribute__((ext_vector_type(4)));
typedef float f32x4 __attribute__((ext_vector_type(4)));
typedef float f32x16 __attribute__((ext_vector_type(16)));

#define HID   1024
#define NHEAD 16
#define HD    64
#define EXPD  4096
#define LSEQ  2048
#define BATCH 4
#define MROWS (BATCH * LSEQ)   // 8192

#if __has_builtin(__builtin_amdgcn_exp2f)
#define EXP2F __builtin_amdgcn_exp2f
#else
#define EXP2F exp2f
#endif

__device__ __forceinline__ void gld_lds16(const bf16_t* g, bf16_t* l) {
  __builtin_amdgcn_global_load_lds(
      (const __attribute__((address_space(1))) void*)g,
      (__attribute__((address_space(3))) void*)l, 16, 0, 0);
}

__device__ __forceinline__ void vmwait(int n) {
  // call sites pass constants; folds to a single s_waitcnt
  if (n == 8)      asm volatile("s_waitcnt vmcnt(8)" ::: "memory");
  else if (n == 6) asm volatile("s_waitcnt vmcnt(6)" ::: "memory");
  else if (n == 4) asm volatile("s_waitcnt vmcnt(4)" ::: "memory");
  else if (n == 3) asm volatile("s_waitcnt vmcnt(3)" ::: "memory");
  else if (n == 0) asm volatile("s_waitcnt vmcnt(0)" ::: "memory");
}

// a'[0:31]=a, a'[32:63]=b[0:31]; b'[0:31]=a[32:63], b'[32:63]=b
__device__ __forceinline__ void swap32(unsigned& a, unsigned& b) {
#if __has_builtin(__builtin_amdgcn_permlane32_swap)
  auto r = __builtin_amdgcn_permlane32_swap(a, b, false, false);
  a = r[0]; b = r[1];
#else
  bool hiL = ((threadIdx.x & 63) >= 32);
  unsigned pa = (unsigned)__shfl_xor((int)a, 32, 64);
  unsigned pb = (unsigned)__shfl_xor((int)b, 32, 64);
  unsigned na = hiL ? pb : a;
  unsigned nb = hiL ? b : pa;
  a = na; b = nb;
#endif
}

__device__ __forceinline__ unsigned pk_bf16(float lo, float hi) {
  bf16_t l = (bf16_t)lo, h = (bf16_t)hi;
  unsigned short ul, uh;
  __builtin_memcpy(&ul, &l, 2);
  __builtin_memcpy(&uh, &h, 2);
  return (unsigned)ul | ((unsigned)uh << 16);
}

// ---------------- convert f32 -> bf16 (x) ----------------
__global__ __launch_bounds__(256) void cvt_bf16(const float* __restrict__ in,
                                                bf16_t* __restrict__ out, int n4) {
  int i = blockIdx.x * 256 + threadIdx.x;
  if (i >= n4) return;
  float4 v = ((const float4*)in)[i];
  bf16x4 o;
  o[0] = (bf16_t)v.x; o[1] = (bf16_t)v.y; o[2] = (bf16_t)v.z; o[3] = (bf16_t)v.w;
  ((bf16x4*)out)[i] = o;
}

// ---------------- transpose + convert: W[K][N] f32 -> Wt[N][K] bf16 ----------------
__global__ __launch_bounds__(256) void transpose_cvt(const float* __restrict__ W,
                                                     bf16_t* __restrict__ Wt,
                                                     int K, int N) {
  __shared__ float tile[32][33];
  int n0 = blockIdx.x * 32, k0 = blockIdx.y * 32;
  int tx = threadIdx.x & 31, ty = threadIdx.x >> 5;
#pragma unroll
  for (int i = 0; i < 32; i += 8)
    tile[ty + i][tx] = W[(size_t)(k0 + ty + i) * N + n0 + tx];
  __syncthreads();
#pragma unroll
  for (int i = 0; i < 32; i += 8)
    Wt[(size_t)(n0 + ty + i) * K + k0 + tx] = (bf16_t)tile[tx][ty + i];
}

// ---------------- transpose V: qkvb V-part -> vT[b*16+h][d][l] bf16 ----------------
__global__ __launch_bounds__(256) void transpose_v(const bf16_t* __restrict__ qkvb,
                                                   bf16_t* __restrict__ vT) {
  __shared__ bf16_t tile[64][65];
  const int l0 = blockIdx.x * 64;
  const int bh = blockIdx.y;
  const int b = bh >> 4, h = bh & 15;
  const int tx = threadIdx.x & 63, ty = threadIdx.x >> 6;
  const bf16_t* src = qkvb + ((size_t)(b * LSEQ + l0)) * 3072 + 2048 + h * 64;
#pragma unroll
  for (int i = 0; i < 16; ++i) {
    int l = ty + 4 * i;
    tile[l][tx] = src[(size_t)l * 3072 + tx];
  }
  __syncthreads();
  bf16_t* dst = vT + ((size_t)bh * HD) * LSEQ + l0;
#pragma unroll
  for (int i = 0; i < 16; ++i) {
    int d = ty + 4 * i;
    dst[(size_t)d * LSEQ + tx] = tile[tx][d];
  }
}

// ---------------- GEMM: C[M][N] = A[M][K] @ Bt[N][K]^T + bias ----------------
// mode 0: bf16 out; mode 1: gelu(tanh) then bf16 out; mode 2: f32 out.
// BM = 256. BN = 256 or 128. BK = 32. 512 thr / 8 waves (2M x 4N).
// 4-slot LDS rotation, 3-deep prefetch, 2 fine phases per K-step.
template <int BN>
__global__ __launch_bounds__(512, 2) void gemm_8p(const bf16_t* __restrict__ A,
                                                  const bf16_t* __restrict__ Bt,
                                                  const float* __restrict__ bias,
                                                  void* __restrict__ C,
                                                  int M, int N, int K, int mode) {
  constexpr int BM = 256;
  constexpr int MI = BM / 32;        // 8 A-frags per wave
  constexpr int NJ = BN / 64;        // 4 or 2 B-frags per wave
  constexpr int BL = BN / 128;       // B gld_lds per thread per K-step (2 or 1)
  constexpr int LOADS = 2 + BL;      // total gld_lds per thread per K-step
  __shared__ bf16_t As[4 * BM * 32];
  __shared__ bf16_t Bs[4 * BN * 32];

  // group-M block swizzle: same-XCD blocks (ids = c mod 8) share an A-strip
  const int nbx = gridDim.x;
  int p = blockIdx.y * nbx + blockIdx.x;
  const int GM = 8;
  int group = p / (GM * nbx);
  int idx = p - group * (GM * nbx);
  const int by = group * GM + (idx & (GM - 1));
  const int bx = idx >> 3;  // GM == 8
  const int n0 = bx * BN, m0 = by * BM;

  const int t = threadIdx.x;
  const int lane = t & 63, w = t >> 6;
  const int wr = w >> 2, wc = w & 3;       // 2 x 4 wave grid
  const int quad = lane >> 4, l16 = lane & 15;

  f32x4 acc[MI][NJ];
#pragma unroll
  for (int i = 0; i < MI; ++i)
#pragma unroll
    for (int j = 0; j < NJ; ++j) acc[i][j] = (f32x4){0.f, 0.f, 0.f, 0.f};

  // loop-invariant per-lane DMA source offsets (chunk-XOR swizzled k-chunk)
  const int r0 = t >> 2;                                       // 0..127
  const unsigned ksw = (((unsigned)t & 3u) ^ ((unsigned)(r0 >> 1) & 3u)) * 8u;
  const unsigned offR0 = (unsigned)r0 * (unsigned)K + ksw;
  const unsigned off128 = offR0 + 128u * (unsigned)K;  // (r+128)>>1 &3 == (r>>1)&3

  const bf16_t* aB = A + (size_t)m0 * K;
  const bf16_t* bB = Bt + (size_t)n0 * K;

  // loop-invariant LDS frag read offsets (elems); chunk = quad ^ ((row>>1)&3)
  unsigned aoff[MI], boff[NJ];
#pragma unroll
  for (int i = 0; i < MI; ++i) {
    int row = wr * (BM / 2) + 16 * i + l16;
    aoff[i] = (unsigned)(row * 32 + (quad ^ ((row >> 1) & 3)) * 8);
  }
#pragma unroll
  for (int j = 0; j < NJ; ++j) {
    int row = wc * (BN / 4) + 16 * j + l16;
    boff[j] = (unsigned)(row * 32 + (quad ^ ((row >> 1) & 3)) * 8);
  }

  auto stageA = [&](int slot, int kk) {
    bf16_t* Asl = As + slot * (BM * 32);
    const bf16_t* aS = aB + kk;
    gld_lds16(aS + offR0, Asl + t * 8);
    gld_lds16(aS + off128, Asl + (t + 512) * 8);
  };
  auto stageB = [&](int slot, int kk) {
    bf16_t* Bsl = Bs + slot * (BN * 32);
    const bf16_t* bS = bB + kk;
    gld_lds16(bS + offR0, Bsl + t * 8);
    if constexpr (BL == 2) gld_lds16(bS + off128, Bsl + (t + 512) * 8);
  };

  // one K-step = 2 fine phases; counted vmcnt before phase-1 barrier.
  auto kstep = [&](int slot, bool doStage, int kk, int waitN) {
    const bf16_t* Asl = As + slot * (BM * 32);
    const bf16_t* Bsl = Bs + slot * (BN * 32);
    const int sslot = (slot + 3) & 3;
    bf16x8 bfr[NJ], af[MI / 2];
    // ---- phase 0: A-half0 + all B reads, stage A ----
#pragma unroll
    for (int i = 0; i < MI / 2; ++i) af[i] = *(const bf16x8*)(Asl + aoff[i]);
#pragma unroll
    for (int j = 0; j < NJ; ++j) bfr[j] = *(const bf16x8*)(Bsl + boff[j]);
    if (doStage) stageA(sslot, kk);
    __builtin_amdgcn_sched_barrier(0);
    __builtin_amdgcn_s_barrier();
    asm volatile("s_waitcnt lgkmcnt(0)" ::: "memory");
    __builtin_amdgcn_sched_barrier(0);
    __builtin_amdgcn_s_setprio(1);
#pragma unroll
    for (int i = 0; i < MI / 2; ++i)
#pragma unroll
      for (int j = 0; j < NJ; ++j)
        acc[i][j] = __builtin_amdgcn_mfma_f32_16x16x32_bf16(af[i], bfr[j], acc[i][j], 0, 0, 0);
    __builtin_amdgcn_s_setprio(0);
    __builtin_amdgcn_sched_barrier(0);
    __builtin_amdgcn_s_barrier();
    // ---- phase 1: A-half1 reads, stage B, counted vmcnt ----
#pragma unroll
    for (int i = 0; i < MI / 2; ++i) af[i] = *(const bf16x8*)(Asl + aoff[MI / 2 + i]);
    if (doStage) stageB(sslot, kk);
    vmwait(waitN);  // tile kt+1 (own loads) landed; barrier publishes block-wide
    __builtin_amdgcn_sched_barrier(0);
    __builtin_amdgcn_s_barrier();
    asm volatile("s_waitcnt lgkmcnt(0)" ::: "memory");
    __builtin_amdgcn_sched_barrier(0);
    __builtin_amdgcn_s_setprio(1);
#pragma unroll
    for (int i = 0; i < MI / 2; ++i)
#pragma unroll
      for (int j = 0; j < NJ; ++j)
        acc[MI / 2 + i][j] =
            __builtin_amdgcn_mfma_f32_16x16x32_bf16(af[i], bfr[j], acc[MI / 2 + i][j], 0, 0, 0);
    __builtin_amdgcn_s_setprio(0);
    __builtin_amdgcn_sched_barrier(0);
    __builtin_amdgcn_s_barrier();
  };

  const int NT = K >> 5;   // K/32 tiles; NT >= 4 required

  // prologue: stage tiles 0..2; tile 0 landed (tiles 1,2 = 2*LOADS in flight)
  stageA(0, 0);  stageB(0, 0);
  stageA(1, 32); stageB(1, 32);
  stageA(2, 64); stageB(2, 64);
  vmwait(2 * LOADS);
  __builtin_amdgcn_s_barrier();

  int kt = 0;
  for (; kt < NT - 3; ++kt)
    kstep(kt & 3, true, (kt + 3) * 32, 2 * LOADS);
  kstep(kt & 3, false, 0, LOADS); ++kt;   // guarantees tile NT-2
  kstep(kt & 3, false, 0, 0);     ++kt;   // guarantees tile NT-1
  kstep(kt & 3, false, 0, -1);            // no wait

#pragma unroll
  for (int i = 0; i < MI; ++i) {
    int rowb = m0 + wr * (BM / 2) + 16 * i + quad * 4;
#pragma unroll
    for (int j = 0; j < NJ; ++j) {
      int col = n0 + wc * (BN / 4) + 16 * j + l16;
      float bv = bias[col];
#pragma unroll
      for (int r = 0; r < 4; ++r) {
        float v = acc[i][j][r] + bv;
        size_t idx = (size_t)(rowb + r) * N + col;
        if (mode == 0) {
          ((bf16_t*)C)[idx] = (bf16_t)v;
        } else if (mode == 1) {
          // tanh-approx gelu (max |err| ~3e-4, threshold 0.109)
          float u = v * (0.7978845608028654f + 0.0356774081f * v * v);
          float e = EXP2F(u * 2.885390082f);  // exp(2u) = 2^(2u*log2e)
          float th = (e - 1.f) / (e + 1.f);
          float gel = 0.5f * v * (1.f + th);
          ((bf16_t*)C)[idx] = (bf16_t)gel;
        } else {
          ((float*)C)[idx] = v;
        }
      }
    }
  }
}

// ---------------- flash attention: 128q/block, operand-swapped, reg-resident P ----------------
// S^T[k][q] = K·(sc·Q)^T  (A=K, B=Q) ; O^T[d][q] = V^T · P^T  (A=V^T, B=P^T in regs)
__global__ __launch_bounds__(256) void attn_kernel(const bf16_t* __restrict__ qkv,
                                                   const bf16_t* __restrict__ vT,
                                                   bf16_t* __restrict__ ob) {
  __shared__ bf16_t smem[3 * 128 * 64];   // 48 KB: Ks | Vts | Qs
  bf16_t* Ks  = smem;           // [128 k][64 d]  unpadded, chunk-XOR swizzle
  bf16_t* Vts = smem + 8192;    // [64 d][128 j]  unpadded, chunk-XOR swizzle
  bf16_t* Qs  = smem + 16384;   // [128 q][64 d]  unpadded, chunk-XOR swizzle
  const int qt = blockIdx.x, h = blockIdx.y, b = blockIdx.z;
  const int t = threadIdx.x, lane = t & 63, w = t >> 6;
  const int l32 = lane & 31, hi = lane >> 5;
  const size_t RS = 3 * HID;
  const int bh = b * NHEAD + h;

  const bf16_t* qbase = qkv + ((size_t)(b * LSEQ + qt * 128)) * RS + h * HD;
  const bf16_t* kbase = qkv + ((size_t)b * LSEQ) * RS + HID + h * HD;
  const bf16_t* vtbase = vT + (size_t)bh * HD * LSEQ;

  // stage Q [128][64] via DMA, source-swizzled
#pragma unroll
  for (int s = 0; s < 4; ++s) {
    int l = t + s * 256;
    int r = l >> 3, c8 = l & 7;
    gld_lds16(qbase + (size_t)r * RS + ((c8 ^ (r & 7)) * 8), Qs + l * 8);
  }
  __syncthreads();

  // hoist Q B-frags (wave w owns q-tile 32w), pre-scaled
  const float sc = 0.18033688011112042f;  // (1/sqrt(64)) * log2(e)
  bf16x8 bq[4];
  {
    int qrow = 32 * w + l32;
#pragma unroll
    for (int c = 0; c < 4; ++c) {
      int y = 2 * c + hi;
      bf16x8 q8 = *(const bf16x8*)(Qs + qrow * 64 + ((y ^ (qrow & 7)) * 8));
#pragma unroll
      for (int e = 0; e < 8; ++e) q8[e] = (bf16_t)((float)q8[e] * sc);
      bq[c] = q8;
    }
  }

  f32x16 accO[2];
#pragma unroll
  for (int dt = 0; dt < 2; ++dt)
#pragma unroll
    for (int e = 0; e < 16; ++e) accO[dt][e] = 0.f;
  float l_acc = 0.f;

  for (int kt = 0; kt < LSEQ / 128; ++kt) {
    __syncthreads();  // prior reads done (iter 0: Q hoist done)
#pragma unroll
    for (int s = 0; s < 4; ++s) {
      int l = t + s * 256;
      int r = l >> 3, c8 = l & 7;
      gld_lds16(kbase + (size_t)(kt * 128 + r) * RS + ((c8 ^ (r & 7)) * 8), Ks + l * 8);
      int rv = l >> 4, c16 = l & 15;
      gld_lds16(vtbase + (size_t)rv * LSEQ + kt * 128 + ((c16 ^ (rv & 7)) * 8), Vts + l * 8);
    }
    __syncthreads();

#pragma unroll
    for (int kt2 = 0; kt2 < 2; ++kt2) {
      // S^T for 2 k-tiles (rows 64*kt2 .. +64) x this wave's 32 q
      f32x16 s0, s1;
#pragma unroll
      for (int e = 0; e < 16; ++e) { s0[e] = 0.f; s1[e] = 0.f; }
#pragma unroll
      for (int c = 0; c < 4; ++c) {
        int y = 2 * c + hi;
        int r0 = (2 * kt2 + 0) * 32 + l32;
        bf16x8 a0 = *(const bf16x8*)(Ks + r0 * 64 + ((y ^ (r0 & 7)) * 8));
        s0 = __builtin_amdgcn_mfma_f32_32x32x16_bf16(a0, bq[c], s0, 0, 0, 0);
        int r1 = (2 * kt2 + 1) * 32 + l32;
        bf16x8 a1 = *(const bf16x8*)(Ks + r1 * 64 + ((y ^ (r1 & 7)) * 8));
        s1 = __builtin_amdgcn_mfma_f32_32x32x16_bf16(a1, bq[c], s1, 0, 0, 0);
      }

      // p = exp2(s); pack to bf16 pairs; assemble P^T B-frags via permlane swaps
      unsigned pf[2][2][4];  // [tile][c2][reg]
#pragma unroll
      for (int tile = 0; tile < 2; ++tile) {
        f32x16& sv = tile ? s1 : s0;
        float p[16];
#pragma unroll
        for (int e = 0; e < 16; ++e) { p[e] = EXP2F(sv[e]); l_acc += p[e]; }
        unsigned lo[4], hi_[4];
#pragma unroll
        for (int g = 0; g < 4; ++g) {
          lo[g] = pk_bf16(p[4 * g + 0], p[4 * g + 1]);
          hi_[g] = pk_bf16(p[4 * g + 2], p[4 * g + 3]);
        }
#pragma unroll
        for (int c2 = 0; c2 < 2; ++c2) {
          unsigned aL = lo[2 * c2], bL = lo[2 * c2 + 1];
          swap32(aL, bL);
          pf[tile][c2][0] = aL; pf[tile][c2][2] = bL;
          unsigned aH = hi_[2 * c2], bH = hi_[2 * c2 + 1];
          swap32(aH, bH);
          pf[tile][c2][1] = aH; pf[tile][c2][3] = bH;
        }
      }

      // O^T += V^T · P^T
#pragma unroll
      for (int dt = 0; dt < 2; ++dt)
#pragma unroll
        for (int tile = 0; tile < 2; ++tile)
#pragma unroll
          for (int c2 = 0; c2 < 2; ++c2) {
            int ktile = 2 * kt2 + tile;
            int c8v = ktile * 4 + c2 * 2 + hi;
            int rv = dt * 32 + l32;
            bf16x8 av = *(const bf16x8*)(Vts + rv * 128 + ((c8v ^ (rv & 7)) * 8));
            union { unsigned u[4]; bf16x8 v; } bp;
            bp.u[0] = pf[tile][c2][0]; bp.u[1] = pf[tile][c2][1];
            bp.u[2] = pf[tile][c2][2]; bp.u[3] = pf[tile][c2][3];
            accO[dt] = __builtin_amdgcn_mfma_f32_32x32x16_bf16(av, bp.v, accO[dt], 0, 0, 0);
          }
    }
  }

  // denominator: col q = l32 per lane; halves hold partial sums
  l_acc += __shfl_xor(l_acc, 32, 64);
  float inv = 1.f / l_acc;

  // epilogue: O^T -> LDS (stride 68) -> coalesced global
  __syncthreads();
  bf16_t* Osh = smem;
  {
    int q = 32 * w + l32;
#pragma unroll
    for (int dt = 0; dt < 2; ++dt)
#pragma unroll
      for (int e = 0; e < 16; ++e) {
        int d = dt * 32 + (e & 3) + 8 * (e >> 2) + 4 * hi;
        Osh[q * 68 + d] = (bf16_t)(accO[dt][e] * inv);
      }
  }
  __syncthreads();
#pragma unroll
  for (int s = 0; s < 4; ++s) {
    int l = t + s * 256;
    int r = l >> 3, c8 = l & 7;
    bf16x8 v = *(const bf16x8*)(Osh + r * 68 + c8 * 8);
    *(bf16x8*)(ob + ((size_t)(b * LSEQ + qt * 128 + r)) * HID + h * HD + c8 * 8) = v;
  }
}

// ---------------- residual add + LayerNorm ----------------
__global__ __launch_bounds__(256) void resid_ln(const float* __restrict__ X,
                                                const float* __restrict__ Y,
                                                const float* __restrict__ g,
                                                const float* __restrict__ be,
                                                float* __restrict__ outf,
                                                bf16_t* __restrict__ outb) {
  const int row = blockIdx.x;
  const int t = threadIdx.x;
  float4 a = ((const float4*)X)[(size_t)row * 256 + t];
  float4 bvec = ((const float4*)Y)[(size_t)row * 256 + t];
  float v0 = a.x + bvec.x, v1 = a.y + bvec.y, v2 = a.z + bvec.z, v3 = a.w + bvec.w;
  float s = v0 + v1 + v2 + v3;
  float s2 = v0 * v0 + v1 * v1 + v2 * v2 + v3 * v3;
#pragma unroll
  for (int msk = 1; msk < 64; msk <<= 1) {
    s += __shfl_xor(s, msk, 64);
    s2 += __shfl_xor(s2, msk, 64);
  }
  __shared__ float red[8];
  int w = t >> 6;
  if ((t & 63) == 0) { red[w] = s; red[w + 4] = s2; }
  __syncthreads();
  s = red[0] + red[1] + red[2] + red[3];
  s2 = red[4] + red[5] + red[6] + red[7];
  float mu = s * (1.f / 1024.f);
  float var = s2 * (1.f / 1024.f) - mu * mu;
  float rstd = rsqrtf(var + 1e-5f);
  float4 gg = ((const float4*)g)[t];
  float4 bb = ((const float4*)be)[t];
  float o0 = (v0 - mu) * rstd * gg.x + bb.x;
  float o1 = (v1 - mu) * rstd * gg.y + bb.y;
  float o2 = (v2 - mu) * rstd * gg.z + bb.z;
  float o3 = (v3 - mu) * rstd * gg.w + bb.w;
  float4 o = {o0, o1, o2, o3};
  ((float4*)outf)[(size_t)row * 256 + t] = o;
  if (outb) {
    bf16x4 ob4;
    ob4[0] = (bf16_t)o0; ob4[1] = (bf16_t)o1; ob4[2] = (bf16_t)o2; ob4[3] = (bf16_t)o3;
    ((bf16x4*)outb)[(size_t)row * 256 + t] = ob4;
  }
}

// ---------------- host ----------------
extern "C" void kernel_launch(void* const* d_in, const int* in_sizes, int n_in,
                              void* d_out, int out_size, void* d_ws, size_t ws_size,
                              hipStream_t stream) {
  const float* x     = (const float*)d_in[0];
  const float* Wqkv  = (const float*)d_in[1];
  const float* bqkv  = (const float*)d_in[2];
  const float* Wproj = (const float*)d_in[3];
  const float* bproj = (const float*)d_in[4];
  const float* W1    = (const float*)d_in[5];
  const float* b1    = (const float*)d_in[6];
  const float* W2    = (const float*)d_in[7];
  const float* b2    = (const float*)d_in[8];
  const float* g1    = (const float*)d_in[9];
  const float* be1   = (const float*)d_in[10];
  const float* g2    = (const float*)d_in[11];
  const float* be2   = (const float*)d_in[12];
  float* out = (float*)d_out;

  char* ws = (char*)d_ws;
  size_t off = 0;
  auto alloc = [&](size_t bytes) -> char* {
    char* p = ws + off;
    off += (bytes + 255) & ~(size_t)255;
    return p;
  };
  bf16_t* wqkvT  = (bf16_t*)alloc((size_t)3072 * 1024 * 2);
  bf16_t* wprojT = (bf16_t*)alloc((size_t)1024 * 1024 * 2);
  bf16_t* w1T    = (bf16_t*)alloc((size_t)4096 * 1024 * 2);
  bf16_t* w2T    = (bf16_t*)alloc((size_t)1024 * 4096 * 2);
  char*   xb_ob  = alloc((size_t)MROWS * HID * 2);
  char*   qkv_ff = alloc((size_t)MROWS * EXPD * 2);
  char*   a_f2   = alloc((size_t)MROWS * HID * 4);
  float*  h      = (float*)alloc((size_t)MROWS * HID * 4);
  bf16_t* hb     = (bf16_t*)alloc((size_t)MROWS * HID * 2);

  bf16_t* xb    = (bf16_t*)xb_ob;
  bf16_t* ob    = (bf16_t*)xb_ob;
  bf16_t* qkvb  = (bf16_t*)qkv_ff;
  bf16_t* ff1b  = (bf16_t*)qkv_ff;
  float*  attnf = (float*)a_f2;
  float*  ff2f  = (float*)a_f2;
  bf16_t* vTg   = hb;  // alias: vT live only qkv->attn; hb live only after LN1

  dim3 blk(256);
  dim3 blk512(512);
  transpose_cvt<<<dim3(3072 / 32, 1024 / 32), blk, 0, stream>>>(Wqkv, wqkvT, 1024, 3072);
  transpose_cvt<<<dim3(1024 / 32, 1024 / 32), blk, 0, stream>>>(Wproj, wprojT, 1024, 1024);
  transpose_cvt<<<dim3(4096 / 32, 1024 / 32), blk, 0, stream>>>(W1, w1T, 1024, 4096);
  transpose_cvt<<<dim3(1024 / 32, 4096 / 32), blk, 0, stream>>>(W2, w2T, 4096, 1024);
  cvt_bf16<<<MROWS * HID / 4 / 256, blk, 0, stream>>>(x, xb, MROWS * HID / 4);

  gemm_8p<256><<<dim3(3072 / 256, MROWS / 256), blk512, 0, stream>>>(xb, wqkvT, bqkv, qkvb,
                                                                     MROWS, 3072, 1024, 0);
  transpose_v<<<dim3(LSEQ / 64, BATCH * NHEAD), blk, 0, stream>>>(qkvb, vTg);
  attn_kernel<<<dim3(LSEQ / 128, NHEAD, BATCH), blk, 0, stream>>>(qkvb, vTg, ob);
  gemm_8p<128><<<dim3(1024 / 128, MROWS / 256), blk512, 0, stream>>>(ob, wprojT, bproj, attnf,
                                                                     MROWS, 1024, 1024, 2);
  resid_ln<<<MROWS, blk, 0, stream>>>(x, attnf, g1, be1, h, hb);
  gemm_8p<256><<<dim3(4096 / 256, MROWS / 256), blk512, 0, stream>>>(hb, w1T, b1, ff1b,
                                                                     MROWS, 4096, 1024, 1);
  gemm_8p<128><<<dim3(1024 / 128, MROWS / 256), blk512, 0, stream>>>(ff1b, w2T, b2, ff2f,
                                                                     MROWS, 1024, 4096, 2);
  resid_ln<<<MROWS, blk, 0, stream>>>(h, ff2f, g2, be2, out, (bf16_t*)nullptr);
}

// Round 3
// 571.665 us; speedup vs baseline: 1.1030x; 1.0959x over previous
//
#include <hip/hip_runtime.h>
#include <hip/hip_bf16.h>
#include <math.h>

// Transformer block, MI355X gfx950.
// R8: GEMM = lean single-barrier counted-vmcnt loop + multi-block TLP.
//   3-slot LDS rotation (2 tiles prefetch), ONE s_barrier + ONE
//   s_waitcnt vmcnt(LOADS) per K-step. Sized for residency:
//   QKV/FF1: 128x256, 512thr, 72KB LDS, launch_bounds(512,4) -> 2 blocks/CU.
//   proj/FF2: 128x128, 256thr, 48KB LDS, launch_bounds(256,3) -> 3 blocks/CU.
//   Rationale: R5-R7 showed schedule shape is a no-op at 1 block/CU
//   (MfmaUtil pinned 23%, 49% no-issue stalls); cross-block wave overlap
//   is the one untested mechanism (m97/m114 implicit overlap).
// Attention unchanged from R4 (operand-swapped, reg-resident P).

typedef __bf16 bf16_t;
typedef __bf16 bf16x8 __attribute__((ext_vector_type(8)));
typedef __bf16 bf16x4 __attribute__((ext_vector_type(4)));
typedef float f32x4 __attribute__((ext_vector_type(4)));
typedef float f32x16 __attribute__((ext_vector_type(16)));

#define HID   1024
#define NHEAD 16
#define HD    64
#define EXPD  4096
#define LSEQ  2048
#define BATCH 4
#define MROWS (BATCH * LSEQ)   // 8192

#if __has_builtin(__builtin_amdgcn_exp2f)
#define EXP2F __builtin_amdgcn_exp2f
#else
#define EXP2F exp2f
#endif

__device__ __forceinline__ void gld_lds16(const bf16_t* g, bf16_t* l) {
  __builtin_amdgcn_global_load_lds(
      (const __attribute__((address_space(1))) void*)g,
      (__attribute__((address_space(3))) void*)l, 16, 0, 0);
}

__device__ __forceinline__ void vmwait(int n) {
  // call sites pass constants; dead branches fold away
  if (n == 4)      asm volatile("s_waitcnt vmcnt(4)" ::: "memory");
  else if (n == 3) asm volatile("s_waitcnt vmcnt(3)" ::: "memory");
  else if (n == 0) asm volatile("s_waitcnt vmcnt(0)" ::: "memory");
}

__device__ __forceinline__ void block_bar() {
  asm volatile("" ::: "memory");
  __builtin_amdgcn_s_barrier();
  asm volatile("" ::: "memory");
}

// a'[0:31]=a, a'[32:63]=b[0:31]; b'[0:31]=a[32:63], b'[32:63]=b
__device__ __forceinline__ void swap32(unsigned& a, unsigned& b) {
#if __has_builtin(__builtin_amdgcn_permlane32_swap)
  auto r = __builtin_amdgcn_permlane32_swap(a, b, false, false);
  a = r[0]; b = r[1];
#else
  bool hiL = ((threadIdx.x & 63) >= 32);
  unsigned pa = (unsigned)__shfl_xor((int)a, 32, 64);
  unsigned pb = (unsigned)__shfl_xor((int)b, 32, 64);
  unsigned na = hiL ? pb : a;
  unsigned nb = hiL ? b : pa;
  a = na; b = nb;
#endif
}

__device__ __forceinline__ unsigned pk_bf16(float lo, float hi) {
  bf16_t l = (bf16_t)lo, h = (bf16_t)hi;
  unsigned short ul, uh;
  __builtin_memcpy(&ul, &l, 2);
  __builtin_memcpy(&uh, &h, 2);
  return (unsigned)ul | ((unsigned)uh << 16);
}

// ---------------- convert f32 -> bf16 (x) ----------------
__global__ __launch_bounds__(256) void cvt_bf16(const float* __restrict__ in,
                                                bf16_t* __restrict__ out, int n4) {
  int i = blockIdx.x * 256 + threadIdx.x;
  if (i >= n4) return;
  float4 v = ((const float4*)in)[i];
  bf16x4 o;
  o[0] = (bf16_t)v.x; o[1] = (bf16_t)v.y; o[2] = (bf16_t)v.z; o[3] = (bf16_t)v.w;
  ((bf16x4*)out)[i] = o;
}

// ---------------- transpose + convert: W[K][N] f32 -> Wt[N][K] bf16 ----------------
__global__ __launch_bounds__(256) void transpose_cvt(const float* __restrict__ W,
                                                     bf16_t* __restrict__ Wt,
                                                     int K, int N) {
  __shared__ float tile[32][33];
  int n0 = blockIdx.x * 32, k0 = blockIdx.y * 32;
  int tx = threadIdx.x & 31, ty = threadIdx.x >> 5;
#pragma unroll
  for (int i = 0; i < 32; i += 8)
    tile[ty + i][tx] = W[(size_t)(k0 + ty + i) * N + n0 + tx];
  __syncthreads();
#pragma unroll
  for (int i = 0; i < 32; i += 8)
    Wt[(size_t)(n0 + ty + i) * K + k0 + tx] = (bf16_t)tile[tx][ty + i];
}

// ---------------- transpose V: qkvb V-part -> vT[b*16+h][d][l] bf16 ----------------
__global__ __launch_bounds__(256) void transpose_v(const bf16_t* __restrict__ qkvb,
                                                   bf16_t* __restrict__ vT) {
  __shared__ bf16_t tile[64][65];
  const int l0 = blockIdx.x * 64;
  const int bh = blockIdx.y;
  const int b = bh >> 4, h = bh & 15;
  const int tx = threadIdx.x & 63, ty = threadIdx.x >> 6;
  const bf16_t* src = qkvb + ((size_t)(b * LSEQ + l0)) * 3072 + 2048 + h * 64;
#pragma unroll
  for (int i = 0; i < 16; ++i) {
    int l = ty + 4 * i;
    tile[l][tx] = src[(size_t)l * 3072 + tx];
  }
  __syncthreads();
  bf16_t* dst = vT + ((size_t)bh * HD) * LSEQ + l0;
#pragma unroll
  for (int i = 0; i < 16; ++i) {
    int d = ty + 4 * i;
    dst[(size_t)d * LSEQ + tx] = tile[tx][d];
  }
}

// ---------------- GEMM: C[M][N] = A[M][K] @ Bt[N][K]^T + bias ----------------
// mode 0: bf16 out; mode 1: gelu(tanh) then bf16 out; mode 2: f32 out.
// BM x BN tile, NTHR threads (WAVES = NTHR/64, wave grid 2 x WAVES/2,
// per-wave output 64x64: 16 MFMA + 8 ds_read_b128 per K-step).
// 3-slot LDS rotation, 2-deep prefetch, 1 barrier + 1 counted vmcnt / K-step.
template <int BM, int BN, int NTHR>
__global__ __launch_bounds__(NTHR, (NTHR == 512 ? 4 : 3))
void gemm_k(const bf16_t* __restrict__ A,
            const bf16_t* __restrict__ Bt,
            const float* __restrict__ bias,
            void* __restrict__ C,
            int M, int N, int K, int mode) {
  constexpr int WC = (NTHR / 64) / 2;        // wave-grid cols (4 or 2)
  constexpr int AL = BM * 4 / NTHR;          // A gld_lds per thread (1 or 2)
  constexpr int BL = BN * 4 / NTHR;          // B gld_lds per thread (2)
  constexpr int LOADS = AL + BL;             // 3 or 4
  constexpr int RSTEP = NTHR >> 2;           // rows covered per load pass
  __shared__ bf16_t As[3 * BM * 32];
  __shared__ bf16_t Bs[3 * BN * 32];

  // group-M block swizzle: same-XCD blocks (ids = c mod 8) share an A-strip
  const int nbx = gridDim.x;
  int p = blockIdx.y * nbx + blockIdx.x;
  const int GM = 8;
  int group = p / (GM * nbx);
  int idx = p - group * (GM * nbx);
  const int by = group * GM + (idx & (GM - 1));
  const int bx = idx >> 3;  // GM == 8
  const int n0 = bx * BN, m0 = by * BM;

  const int t = threadIdx.x;
  const int lane = t & 63, w = t >> 6;
  const int wr = w / WC, wc = w % WC;
  const int quad = lane >> 4, l16 = lane & 15;

  f32x4 acc[4][4];
#pragma unroll
  for (int i = 0; i < 4; ++i)
#pragma unroll
    for (int j = 0; j < 4; ++j) acc[i][j] = (f32x4){0.f, 0.f, 0.f, 0.f};

  // loop-invariant per-lane DMA source offsets (chunk-XOR swizzled k-chunk)
  const int r0 = t >> 2;
  const unsigned ksw = (((unsigned)t & 3u) ^ ((unsigned)(r0 >> 1) & 3u)) * 8u;
  const unsigned offR0 = (unsigned)r0 * (unsigned)K + ksw;
  // row steps of RSTEP (64/128) preserve (r>>1)&3 -> same swizzle

  const bf16_t* aB = A + (size_t)m0 * K;
  const bf16_t* bB = Bt + (size_t)n0 * K;

  // loop-invariant LDS frag read offsets (elems); chunk = quad ^ ((row>>1)&3)
  unsigned aoff[4], boff[4];
#pragma unroll
  for (int i = 0; i < 4; ++i) {
    int row = wr * 64 + 16 * i + l16;
    aoff[i] = (unsigned)(row * 32 + (quad ^ ((row >> 1) & 3)) * 8);
  }
#pragma unroll
  for (int j = 0; j < 4; ++j) {
    int row = wc * 64 + 16 * j + l16;
    boff[j] = (unsigned)(row * 32 + (quad ^ ((row >> 1) & 3)) * 8);
  }

  auto stage = [&](int slot, int kk) {
    bf16_t* Asl = As + slot * (BM * 32);
    bf16_t* Bsl = Bs + slot * (BN * 32);
    const bf16_t* aS = aB + kk;
    const bf16_t* bS = bB + kk;
#pragma unroll
    for (int a = 0; a < AL; ++a)
      gld_lds16(aS + offR0 + (size_t)a * RSTEP * K, Asl + (t + a * NTHR) * 8);
#pragma unroll
    for (int b = 0; b < BL; ++b)
      gld_lds16(bS + offR0 + (size_t)b * RSTEP * K, Bsl + (t + b * NTHR) * 8);
  };

  const int NT = K >> 5;   // K/32 tiles; NT >= 3 required

  // prologue: stage tiles 0,1; wait tile 0
  stage(0, 0);
  stage(1, 32);
  vmwait(LOADS);
  block_bar();

  int cs = 0;  // LDS slot holding tile kt
  for (int kt = 0; kt < NT; ++kt) {
    if (kt < NT - 2) {
      int ss = cs == 0 ? 2 : cs - 1;   // (cs+2)%3 — freed by last barrier
      stage(ss, (kt + 2) * 32);
    }
    const bf16_t* Asl = As + cs * (BM * 32);
    const bf16_t* Bsl = Bs + cs * (BN * 32);
    bf16x8 af[4], bfr[4];
#pragma unroll
    for (int i = 0; i < 4; ++i) af[i] = *(const bf16x8*)(Asl + aoff[i]);
#pragma unroll
    for (int j = 0; j < 4; ++j) bfr[j] = *(const bf16x8*)(Bsl + boff[j]);
    __builtin_amdgcn_s_setprio(1);
#pragma unroll
    for (int i = 0; i < 4; ++i)
#pragma unroll
      for (int j = 0; j < 4; ++j)
        acc[i][j] = __builtin_amdgcn_mfma_f32_16x16x32_bf16(af[i], bfr[j], acc[i][j], 0, 0, 0);
    __builtin_amdgcn_s_setprio(0);
    if (kt < NT - 2)      vmwait(LOADS);  // tile kt+1 landed (kt+2 in flight)
    else if (kt == NT - 2) vmwait(0);     // tile NT-1 landed
    if (kt < NT - 1) block_bar();
    cs = cs == 2 ? 0 : cs + 1;
  }

#pragma unroll
  for (int i = 0; i < 4; ++i) {
    int rowb = m0 + wr * 64 + 16 * i + quad * 4;
#pragma unroll
    for (int j = 0; j < 4; ++j) {
      int col = n0 + wc * 64 + 16 * j + l16;
      float bv = bias[col];
#pragma unroll
      for (int r = 0; r < 4; ++r) {
        float v = acc[i][j][r] + bv;
        size_t idx = (size_t)(rowb + r) * N + col;
        if (mode == 0) {
          ((bf16_t*)C)[idx] = (bf16_t)v;
        } else if (mode == 1) {
          // tanh-approx gelu (max |err| ~3e-4, threshold 0.109)
          float u = v * (0.7978845608028654f + 0.0356774081f * v * v);
          float e = EXP2F(u * 2.885390082f);  // exp(2u) = 2^(2u*log2e)
          float th = (e - 1.f) / (e + 1.f);
          float gel = 0.5f * v * (1.f + th);
          ((bf16_t*)C)[idx] = (bf16_t)gel;
        } else {
          ((float*)C)[idx] = v;
        }
      }
    }
  }
}

// ---------------- flash attention: 128q/block, operand-swapped, reg-resident P ----------------
// S^T[k][q] = K·(sc·Q)^T  (A=K, B=Q) ; O^T[d][q] = V^T · P^T  (A=V^T, B=P^T in regs)
__global__ __launch_bounds__(256) void attn_kernel(const bf16_t* __restrict__ qkv,
                                                   const bf16_t* __restrict__ vT,
                                                   bf16_t* __restrict__ ob) {
  __shared__ bf16_t smem[3 * 128 * 64];   // 48 KB: Ks | Vts | Qs
  bf16_t* Ks  = smem;           // [128 k][64 d]  unpadded, chunk-XOR swizzle
  bf16_t* Vts = smem + 8192;    // [64 d][128 j]  unpadded, chunk-XOR swizzle
  bf16_t* Qs  = smem + 16384;   // [128 q][64 d]  unpadded, chunk-XOR swizzle
  const int qt = blockIdx.x, h = blockIdx.y, b = blockIdx.z;
  const int t = threadIdx.x, lane = t & 63, w = t >> 6;
  const int l32 = lane & 31, hi = lane >> 5;
  const size_t RS = 3 * HID;
  const int bh = b * NHEAD + h;

  const bf16_t* qbase = qkv + ((size_t)(b * LSEQ + qt * 128)) * RS + h * HD;
  const bf16_t* kbase = qkv + ((size_t)b * LSEQ) * RS + HID + h * HD;
  const bf16_t* vtbase = vT + (size_t)bh * HD * LSEQ;

  // stage Q [128][64] via DMA, source-swizzled
#pragma unroll
  for (int s = 0; s < 4; ++s) {
    int l = t + s * 256;
    int r = l >> 3, c8 = l & 7;
    gld_lds16(qbase + (size_t)r * RS + ((c8 ^ (r & 7)) * 8), Qs + l * 8);
  }
  __syncthreads();

  // hoist Q B-frags (wave w owns q-tile 32w), pre-scaled
  const float sc = 0.18033688011112042f;  // (1/sqrt(64)) * log2(e)
  bf16x8 bq[4];
  {
    int qrow = 32 * w + l32;
#pragma unroll
    for (int c = 0; c < 4; ++c) {
      int y = 2 * c + hi;
      bf16x8 q8 = *(const bf16x8*)(Qs + qrow * 64 + ((y ^ (qrow & 7)) * 8));
#pragma unroll
      for (int e = 0; e < 8; ++e) q8[e] = (bf16_t)((float)q8[e] * sc);
      bq[c] = q8;
    }
  }

  f32x16 accO[2];
#pragma unroll
  for (int dt = 0; dt < 2; ++dt)
#pragma unroll
    for (int e = 0; e < 16; ++e) accO[dt][e] = 0.f;
  float l_acc = 0.f;

  for (int kt = 0; kt < LSEQ / 128; ++kt) {
    __syncthreads();  // prior reads done (iter 0: Q hoist done)
#pragma unroll
    for (int s = 0; s < 4; ++s) {
      int l = t + s * 256;
      int r = l >> 3, c8 = l & 7;
      gld_lds16(kbase + (size_t)(kt * 128 + r) * RS + ((c8 ^ (r & 7)) * 8), Ks + l * 8);
      int rv = l >> 4, c16 = l & 15;
      gld_lds16(vtbase + (size_t)rv * LSEQ + kt * 128 + ((c16 ^ (rv & 7)) * 8), Vts + l * 8);
    }
    __syncthreads();

#pragma unroll
    for (int kt2 = 0; kt2 < 2; ++kt2) {
      // S^T for 2 k-tiles (rows 64*kt2 .. +64) x this wave's 32 q
      f32x16 s0, s1;
#pragma unroll
      for (int e = 0; e < 16; ++e) { s0[e] = 0.f; s1[e] = 0.f; }
#pragma unroll
      for (int c = 0; c < 4; ++c) {
        int y = 2 * c + hi;
        int r0 = (2 * kt2 + 0) * 32 + l32;
        bf16x8 a0 = *(const bf16x8*)(Ks + r0 * 64 + ((y ^ (r0 & 7)) * 8));
        s0 = __builtin_amdgcn_mfma_f32_32x32x16_bf16(a0, bq[c], s0, 0, 0, 0);
        int r1 = (2 * kt2 + 1) * 32 + l32;
        bf16x8 a1 = *(const bf16x8*)(Ks + r1 * 64 + ((y ^ (r1 & 7)) * 8));
        s1 = __builtin_amdgcn_mfma_f32_32x32x16_bf16(a1, bq[c], s1, 0, 0, 0);
      }

      // p = exp2(s); pack to bf16 pairs; assemble P^T B-frags via permlane swaps
      unsigned pf[2][2][4];  // [tile][c2][reg]
#pragma unroll
      for (int tile = 0; tile < 2; ++tile) {
        f32x16& sv = tile ? s1 : s0;
        float p[16];
#pragma unroll
        for (int e = 0; e < 16; ++e) { p[e] = EXP2F(sv[e]); l_acc += p[e]; }
        unsigned lo[4], hi_[4];
#pragma unroll
        for (int g = 0; g < 4; ++g) {
          lo[g] = pk_bf16(p[4 * g + 0], p[4 * g + 1]);
          hi_[g] = pk_bf16(p[4 * g + 2], p[4 * g + 3]);
        }
#pragma unroll
        for (int c2 = 0; c2 < 2; ++c2) {
          unsigned aL = lo[2 * c2], bL = lo[2 * c2 + 1];
          swap32(aL, bL);
          pf[tile][c2][0] = aL; pf[tile][c2][2] = bL;
          unsigned aH = hi_[2 * c2], bH = hi_[2 * c2 + 1];
          swap32(aH, bH);
          pf[tile][c2][1] = aH; pf[tile][c2][3] = bH;
        }
      }

      // O^T += V^T · P^T
#pragma unroll
      for (int dt = 0; dt < 2; ++dt)
#pragma unroll
        for (int tile = 0; tile < 2; ++tile)
#pragma unroll
          for (int c2 = 0; c2 < 2; ++c2) {
            int ktile = 2 * kt2 + tile;
            int c8v = ktile * 4 + c2 * 2 + hi;
            int rv = dt * 32 + l32;
            bf16x8 av = *(const bf16x8*)(Vts + rv * 128 + ((c8v ^ (rv & 7)) * 8));
            union { unsigned u[4]; bf16x8 v; } bp;
            bp.u[0] = pf[tile][c2][0]; bp.u[1] = pf[tile][c2][1];
            bp.u[2] = pf[tile][c2][2]; bp.u[3] = pf[tile][c2][3];
            accO[dt] = __builtin_amdgcn_mfma_f32_32x32x16_bf16(av, bp.v, accO[dt], 0, 0, 0);
          }
    }
  }

  // denominator: col q = l32 per lane; halves hold partial sums
  l_acc += __shfl_xor(l_acc, 32, 64);
  float inv = 1.f / l_acc;

  // epilogue: O^T -> LDS (stride 68) -> coalesced global
  __syncthreads();
  bf16_t* Osh = smem;
  {
    int q = 32 * w + l32;
#pragma unroll
    for (int dt = 0; dt < 2; ++dt)
#pragma unroll
      for (int e = 0; e < 16; ++e) {
        int d = dt * 32 + (e & 3) + 8 * (e >> 2) + 4 * hi;
        Osh[q * 68 + d] = (bf16_t)(accO[dt][e] * inv);
      }
  }
  __syncthreads();
#pragma unroll
  for (int s = 0; s < 4; ++s) {
    int l = t + s * 256;
    int r = l >> 3, c8 = l & 7;
    bf16x8 v = *(const bf16x8*)(Osh + r * 68 + c8 * 8);
    *(bf16x8*)(ob + ((size_t)(b * LSEQ + qt * 128 + r)) * HID + h * HD + c8 * 8) = v;
  }
}

// ---------------- residual add + LayerNorm ----------------
__global__ __launch_bounds__(256) void resid_ln(const float* __restrict__ X,
                                                const float* __restrict__ Y,
                                                const float* __restrict__ g,
                                                const float* __restrict__ be,
                                                float* __restrict__ outf,
                                                bf16_t* __restrict__ outb) {
  const int row = blockIdx.x;
  const int t = threadIdx.x;
  float4 a = ((const float4*)X)[(size_t)row * 256 + t];
  float4 bvec = ((const float4*)Y)[(size_t)row * 256 + t];
  float v0 = a.x + bvec.x, v1 = a.y + bvec.y, v2 = a.z + bvec.z, v3 = a.w + bvec.w;
  float s = v0 + v1 + v2 + v3;
  float s2 = v0 * v0 + v1 * v1 + v2 * v2 + v3 * v3;
#pragma unroll
  for (int msk = 1; msk < 64; msk <<= 1) {
    s += __shfl_xor(s, msk, 64);
    s2 += __shfl_xor(s2, msk, 64);
  }
  __shared__ float red[8];
  int w = t >> 6;
  if ((t & 63) == 0) { red[w] = s; red[w + 4] = s2; }
  __syncthreads();
  s = red[0] + red[1] + red[2] + red[3];
  s2 = red[4] + red[5] + red[6] + red[7];
  float mu = s * (1.f / 1024.f);
  float var = s2 * (1.f / 1024.f) - mu * mu;
  float rstd = rsqrtf(var + 1e-5f);
  float4 gg = ((const float4*)g)[t];
  float4 bb = ((const float4*)be)[t];
  float o0 = (v0 - mu) * rstd * gg.x + bb.x;
  float o1 = (v1 - mu) * rstd * gg.y + bb.y;
  float o2 = (v2 - mu) * rstd * gg.z + bb.z;
  float o3 = (v3 - mu) * rstd * gg.w + bb.w;
  float4 o = {o0, o1, o2, o3};
  ((float4*)outf)[(size_t)row * 256 + t] = o;
  if (outb) {
    bf16x4 ob4;
    ob4[0] = (bf16_t)o0; ob4[1] = (bf16_t)o1; ob4[2] = (bf16_t)o2; ob4[3] = (bf16_t)o3;
    ((bf16x4*)outb)[(size_t)row * 256 + t] = ob4;
  }
}

// ---------------- host ----------------
extern "C" void kernel_launch(void* const* d_in, const int* in_sizes, int n_in,
                              void* d_out, int out_size, void* d_ws, size_t ws_size,
                              hipStream_t stream) {
  const float* x     = (const float*)d_in[0];
  const float* Wqkv  = (const float*)d_in[1];
  const float* bqkv  = (const float*)d_in[2];
  const float* Wproj = (const float*)d_in[3];
  const float* bproj = (const float*)d_in[4];
  const float* W1    = (const float*)d_in[5];
  const float* b1    = (const float*)d_in[6];
  const float* W2    = (const float*)d_in[7];
  const float* b2    = (const float*)d_in[8];
  const float* g1    = (const float*)d_in[9];
  const float* be1   = (const float*)d_in[10];
  const float* g2    = (const float*)d_in[11];
  const float* be2   = (const float*)d_in[12];
  float* out = (float*)d_out;

  char* ws = (char*)d_ws;
  size_t off = 0;
  auto alloc = [&](size_t bytes) -> char* {
    char* p = ws + off;
    off += (bytes + 255) & ~(size_t)255;
    return p;
  };
  bf16_t* wqkvT  = (bf16_t*)alloc((size_t)3072 * 1024 * 2);
  bf16_t* wprojT = (bf16_t*)alloc((size_t)1024 * 1024 * 2);
  bf16_t* w1T    = (bf16_t*)alloc((size_t)4096 * 1024 * 2);
  bf16_t* w2T    = (bf16_t*)alloc((size_t)1024 * 4096 * 2);
  char*   xb_ob  = alloc((size_t)MROWS * HID * 2);
  char*   qkv_ff = alloc((size_t)MROWS * EXPD * 2);
  char*   a_f2   = alloc((size_t)MROWS * HID * 4);
  float*  h      = (float*)alloc((size_t)MROWS * HID * 4);
  bf16_t* hb     = (bf16_t*)alloc((size_t)MROWS * HID * 2);

  bf16_t* xb    = (bf16_t*)xb_ob;
  bf16_t* ob    = (bf16_t*)xb_ob;
  bf16_t* qkvb  = (bf16_t*)qkv_ff;
  bf16_t* ff1b  = (bf16_t*)qkv_ff;
  float*  attnf = (float*)a_f2;
  float*  ff2f  = (float*)a_f2;
  bf16_t* vTg   = hb;  // alias: vT live only qkv->attn; hb live only after LN1

  dim3 blk(256);
  dim3 blk512(512);
  transpose_cvt<<<dim3(3072 / 32, 1024 / 32), blk, 0, stream>>>(Wqkv, wqkvT, 1024, 3072);
  transpose_cvt<<<dim3(1024 / 32, 1024 / 32), blk, 0, stream>>>(Wproj, wprojT, 1024, 1024);
  transpose_cvt<<<dim3(4096 / 32, 1024 / 32), blk, 0, stream>>>(W1, w1T, 1024, 4096);
  transpose_cvt<<<dim3(1024 / 32, 4096 / 32), blk, 0, stream>>>(W2, w2T, 4096, 1024);
  cvt_bf16<<<MROWS * HID / 4 / 256, blk, 0, stream>>>(x, xb, MROWS * HID / 4);

  gemm_k<128, 256, 512><<<dim3(3072 / 256, MROWS / 128), blk512, 0, stream>>>(
      xb, wqkvT, bqkv, qkvb, MROWS, 3072, 1024, 0);
  transpose_v<<<dim3(LSEQ / 64, BATCH * NHEAD), blk, 0, stream>>>(qkvb, vTg);
  attn_kernel<<<dim3(LSEQ / 128, NHEAD, BATCH), blk, 0, stream>>>(qkvb, vTg, ob);
  gemm_k<128, 128, 256><<<dim3(1024 / 128, MROWS / 128), blk, 0, stream>>>(
      ob, wprojT, bproj, attnf, MROWS, 1024, 1024, 2);
  resid_ln<<<MROWS, blk, 0, stream>>>(x, attnf, g1, be1, h, hb);
  gemm_k<128, 256, 512><<<dim3(4096 / 256, MROWS / 128), blk512, 0, stream>>>(
      hb, w1T, b1, ff1b, MROWS, 4096, 1024, 1);
  gemm_k<128, 128, 256><<<dim3(1024 / 128, MROWS / 128), blk, 0, stream>>>(
      ff1b, w2T, b2, ff2f, MROWS, 1024, 4096, 2);
  resid_ln<<<MROWS, blk, 0, stream>>>(h, ff2f, g2, be2, out, (bf16_t*)nullptr);
}

// Round 4
// 569.082 us; speedup vs baseline: 1.1080x; 1.0045x over previous
//
#include <hip/hip_runtime.h>
#include <hip/hip_bf16.h>
#include <math.h>

// Transformer block, MI355X gfx950.
// R9: attention K/V staging double-buffered with counted vmcnt (R8's GEMM
//   mechanism applied to attn): 2 K/V LDS slots (80 KB total, 2 blocks/CU),
//   stage kt+1 before computing kt, s_waitcnt vmcnt(8) instead of the
//   __syncthreads vmcnt(0) drain; s_setprio around attn MFMA clusters.
// GEMM unchanged from R8 (lean single-barrier counted-vmcnt + multi-block TLP):
//   QKV/FF1: 128x256, 512thr, 72KB LDS, launch_bounds(512,4) -> 2 blocks/CU.
//   proj/FF2: 128x128, 256thr, 48KB LDS, launch_bounds(256,3) -> 3 blocks/CU.

typedef __bf16 bf16_t;
typedef __bf16 bf16x8 __attribute__((ext_vector_type(8)));
typedef __bf16 bf16x4 __attribute__((ext_vector_type(4)));
typedef float f32x4 __attribute__((ext_vector_type(4)));
typedef float f32x16 __attribute__((ext_vector_type(16)));

#define HID   1024
#define NHEAD 16
#define HD    64
#define EXPD  4096
#define LSEQ  2048
#define BATCH 4
#define MROWS (BATCH * LSEQ)   // 8192

#if __has_builtin(__builtin_amdgcn_exp2f)
#define EXP2F __builtin_amdgcn_exp2f
#else
#define EXP2F exp2f
#endif

__device__ __forceinline__ void gld_lds16(const bf16_t* g, bf16_t* l) {
  __builtin_amdgcn_global_load_lds(
      (const __attribute__((address_space(1))) void*)g,
      (__attribute__((address_space(3))) void*)l, 16, 0, 0);
}

__device__ __forceinline__ void vmwait(int n) {
  // call sites pass constants; dead branches fold away
  if (n == 8)      asm volatile("s_waitcnt vmcnt(8)" ::: "memory");
  else if (n == 4) asm volatile("s_waitcnt vmcnt(4)" ::: "memory");
  else if (n == 3) asm volatile("s_waitcnt vmcnt(3)" ::: "memory");
  else if (n == 0) asm volatile("s_waitcnt vmcnt(0)" ::: "memory");
}

__device__ __forceinline__ void block_bar() {
  asm volatile("" ::: "memory");
  __builtin_amdgcn_s_barrier();
  asm volatile("" ::: "memory");
}

// a'[0:31]=a, a'[32:63]=b[0:31]; b'[0:31]=a[32:63], b'[32:63]=b
__device__ __forceinline__ void swap32(unsigned& a, unsigned& b) {
#if __has_builtin(__builtin_amdgcn_permlane32_swap)
  auto r = __builtin_amdgcn_permlane32_swap(a, b, false, false);
  a = r[0]; b = r[1];
#else
  bool hiL = ((threadIdx.x & 63) >= 32);
  unsigned pa = (unsigned)__shfl_xor((int)a, 32, 64);
  unsigned pb = (unsigned)__shfl_xor((int)b, 32, 64);
  unsigned na = hiL ? pb : a;
  unsigned nb = hiL ? b : pa;
  a = na; b = nb;
#endif
}

__device__ __forceinline__ unsigned pk_bf16(float lo, float hi) {
  bf16_t l = (bf16_t)lo, h = (bf16_t)hi;
  unsigned short ul, uh;
  __builtin_memcpy(&ul, &l, 2);
  __builtin_memcpy(&uh, &h, 2);
  return (unsigned)ul | ((unsigned)uh << 16);
}

// ---------------- convert f32 -> bf16 (x) ----------------
__global__ __launch_bounds__(256) void cvt_bf16(const float* __restrict__ in,
                                                bf16_t* __restrict__ out, int n4) {
  int i = blockIdx.x * 256 + threadIdx.x;
  if (i >= n4) return;
  float4 v = ((const float4*)in)[i];
  bf16x4 o;
  o[0] = (bf16_t)v.x; o[1] = (bf16_t)v.y; o[2] = (bf16_t)v.z; o[3] = (bf16_t)v.w;
  ((bf16x4*)out)[i] = o;
}

// ---------------- transpose + convert: W[K][N] f32 -> Wt[N][K] bf16 ----------------
__global__ __launch_bounds__(256) void transpose_cvt(const float* __restrict__ W,
                                                     bf16_t* __restrict__ Wt,
                                                     int K, int N) {
  __shared__ float tile[32][33];
  int n0 = blockIdx.x * 32, k0 = blockIdx.y * 32;
  int tx = threadIdx.x & 31, ty = threadIdx.x >> 5;
#pragma unroll
  for (int i = 0; i < 32; i += 8)
    tile[ty + i][tx] = W[(size_t)(k0 + ty + i) * N + n0 + tx];
  __syncthreads();
#pragma unroll
  for (int i = 0; i < 32; i += 8)
    Wt[(size_t)(n0 + ty + i) * K + k0 + tx] = (bf16_t)tile[tx][ty + i];
}

// ---------------- transpose V: qkvb V-part -> vT[b*16+h][d][l] bf16 ----------------
__global__ __launch_bounds__(256) void transpose_v(const bf16_t* __restrict__ qkvb,
                                                   bf16_t* __restrict__ vT) {
  __shared__ bf16_t tile[64][65];
  const int l0 = blockIdx.x * 64;
  const int bh = blockIdx.y;
  const int b = bh >> 4, h = bh & 15;
  const int tx = threadIdx.x & 63, ty = threadIdx.x >> 6;
  const bf16_t* src = qkvb + ((size_t)(b * LSEQ + l0)) * 3072 + 2048 + h * 64;
#pragma unroll
  for (int i = 0; i < 16; ++i) {
    int l = ty + 4 * i;
    tile[l][tx] = src[(size_t)l * 3072 + tx];
  }
  __syncthreads();
  bf16_t* dst = vT + ((size_t)bh * HD) * LSEQ + l0;
#pragma unroll
  for (int i = 0; i < 16; ++i) {
    int d = ty + 4 * i;
    dst[(size_t)d * LSEQ + tx] = tile[tx][d];
  }
}

// ---------------- GEMM: C[M][N] = A[M][K] @ Bt[N][K]^T + bias ----------------
// mode 0: bf16 out; mode 1: gelu(tanh) then bf16 out; mode 2: f32 out.
// BM x BN tile, NTHR threads (WAVES = NTHR/64, wave grid 2 x WAVES/2,
// per-wave output 64x64: 16 MFMA + 8 ds_read_b128 per K-step).
// 3-slot LDS rotation, 2-deep prefetch, 1 barrier + 1 counted vmcnt / K-step.
template <int BM, int BN, int NTHR>
__global__ __launch_bounds__(NTHR, (NTHR == 512 ? 4 : 3))
void gemm_k(const bf16_t* __restrict__ A,
            const bf16_t* __restrict__ Bt,
            const float* __restrict__ bias,
            void* __restrict__ C,
            int M, int N, int K, int mode) {
  constexpr int WC = (NTHR / 64) / 2;        // wave-grid cols (4 or 2)
  constexpr int AL = BM * 4 / NTHR;          // A gld_lds per thread (1 or 2)
  constexpr int BL = BN * 4 / NTHR;          // B gld_lds per thread (2)
  constexpr int LOADS = AL + BL;             // 3 or 4
  constexpr int RSTEP = NTHR >> 2;           // rows covered per load pass
  __shared__ bf16_t As[3 * BM * 32];
  __shared__ bf16_t Bs[3 * BN * 32];

  // group-M block swizzle: same-XCD blocks (ids = c mod 8) share an A-strip
  const int nbx = gridDim.x;
  int p = blockIdx.y * nbx + blockIdx.x;
  const int GM = 8;
  int group = p / (GM * nbx);
  int idx = p - group * (GM * nbx);
  const int by = group * GM + (idx & (GM - 1));
  const int bx = idx >> 3;  // GM == 8
  const int n0 = bx * BN, m0 = by * BM;

  const int t = threadIdx.x;
  const int lane = t & 63, w = t >> 6;
  const int wr = w / WC, wc = w % WC;
  const int quad = lane >> 4, l16 = lane & 15;

  f32x4 acc[4][4];
#pragma unroll
  for (int i = 0; i < 4; ++i)
#pragma unroll
    for (int j = 0; j < 4; ++j) acc[i][j] = (f32x4){0.f, 0.f, 0.f, 0.f};

  // loop-invariant per-lane DMA source offsets (chunk-XOR swizzled k-chunk)
  const int r0 = t >> 2;
  const unsigned ksw = (((unsigned)t & 3u) ^ ((unsigned)(r0 >> 1) & 3u)) * 8u;
  const unsigned offR0 = (unsigned)r0 * (unsigned)K + ksw;
  // row steps of RSTEP (64/128) preserve (r>>1)&3 -> same swizzle

  const bf16_t* aB = A + (size_t)m0 * K;
  const bf16_t* bB = Bt + (size_t)n0 * K;

  // loop-invariant LDS frag read offsets (elems); chunk = quad ^ ((row>>1)&3)
  unsigned aoff[4], boff[4];
#pragma unroll
  for (int i = 0; i < 4; ++i) {
    int row = wr * 64 + 16 * i + l16;
    aoff[i] = (unsigned)(row * 32 + (quad ^ ((row >> 1) & 3)) * 8);
  }
#pragma unroll
  for (int j = 0; j < 4; ++j) {
    int row = wc * 64 + 16 * j + l16;
    boff[j] = (unsigned)(row * 32 + (quad ^ ((row >> 1) & 3)) * 8);
  }

  auto stage = [&](int slot, int kk) {
    bf16_t* Asl = As + slot * (BM * 32);
    bf16_t* Bsl = Bs + slot * (BN * 32);
    const bf16_t* aS = aB + kk;
    const bf16_t* bS = bB + kk;
#pragma unroll
    for (int a = 0; a < AL; ++a)
      gld_lds16(aS + offR0 + (size_t)a * RSTEP * K, Asl + (t + a * NTHR) * 8);
#pragma unroll
    for (int b = 0; b < BL; ++b)
      gld_lds16(bS + offR0 + (size_t)b * RSTEP * K, Bsl + (t + b * NTHR) * 8);
  };

  const int NT = K >> 5;   // K/32 tiles; NT >= 3 required

  // prologue: stage tiles 0,1; wait tile 0
  stage(0, 0);
  stage(1, 32);
  vmwait(LOADS);
  block_bar();

  int cs = 0;  // LDS slot holding tile kt
  for (int kt = 0; kt < NT; ++kt) {
    if (kt < NT - 2) {
      int ss = cs == 0 ? 2 : cs - 1;   // (cs+2)%3 — freed by last barrier
      stage(ss, (kt + 2) * 32);
    }
    const bf16_t* Asl = As + cs * (BM * 32);
    const bf16_t* Bsl = Bs + cs * (BN * 32);
    bf16x8 af[4], bfr[4];
#pragma unroll
    for (int i = 0; i < 4; ++i) af[i] = *(const bf16x8*)(Asl + aoff[i]);
#pragma unroll
    for (int j = 0; j < 4; ++j) bfr[j] = *(const bf16x8*)(Bsl + boff[j]);
    __builtin_amdgcn_s_setprio(1);
#pragma unroll
    for (int i = 0; i < 4; ++i)
#pragma unroll
      for (int j = 0; j < 4; ++j)
        acc[i][j] = __builtin_amdgcn_mfma_f32_16x16x32_bf16(af[i], bfr[j], acc[i][j], 0, 0, 0);
    __builtin_amdgcn_s_setprio(0);
    if (kt < NT - 2)      vmwait(LOADS);  // tile kt+1 landed (kt+2 in flight)
    else if (kt == NT - 2) vmwait(0);     // tile NT-1 landed
    if (kt < NT - 1) block_bar();
    cs = cs == 2 ? 0 : cs + 1;
  }

#pragma unroll
  for (int i = 0; i < 4; ++i) {
    int rowb = m0 + wr * 64 + 16 * i + quad * 4;
#pragma unroll
    for (int j = 0; j < 4; ++j) {
      int col = n0 + wc * 64 + 16 * j + l16;
      float bv = bias[col];
#pragma unroll
      for (int r = 0; r < 4; ++r) {
        float v = acc[i][j][r] + bv;
        size_t idx = (size_t)(rowb + r) * N + col;
        if (mode == 0) {
          ((bf16_t*)C)[idx] = (bf16_t)v;
        } else if (mode == 1) {
          // tanh-approx gelu (max |err| ~3e-4, threshold 0.109)
          float u = v * (0.7978845608028654f + 0.0356774081f * v * v);
          float e = EXP2F(u * 2.885390082f);  // exp(2u) = 2^(2u*log2e)
          float th = (e - 1.f) / (e + 1.f);
          float gel = 0.5f * v * (1.f + th);
          ((bf16_t*)C)[idx] = (bf16_t)gel;
        } else {
          ((float*)C)[idx] = v;
        }
      }
    }
  }
}

// ---------------- flash attention: 128q/block, operand-swapped, reg-resident P ----------------
// S^T[k][q] = K·(sc·Q)^T  (A=K, B=Q) ; O^T[d][q] = V^T · P^T  (A=V^T, B=P^T in regs)
// R9: K/V double-buffered (2 slots) + counted vmcnt(8); 80 KB LDS, 2 blocks/CU.
__global__ __launch_bounds__(256, 2) void attn_kernel(const bf16_t* __restrict__ qkv,
                                                      const bf16_t* __restrict__ vT,
                                                      bf16_t* __restrict__ ob) {
  __shared__ bf16_t smem[5 * 128 * 64];   // 80 KB: [Ks|Vts] x2 slots | Qs
  bf16_t* Qs = smem + 32768;    // [128 q][64 d]  unpadded, chunk-XOR swizzle
  const int qt = blockIdx.x, h = blockIdx.y, b = blockIdx.z;
  const int t = threadIdx.x, lane = t & 63, w = t >> 6;
  const int l32 = lane & 31, hi = lane >> 5;
  const size_t RS = 3 * HID;
  const int bh = b * NHEAD + h;

  const bf16_t* qbase = qkv + ((size_t)(b * LSEQ + qt * 128)) * RS + h * HD;
  const bf16_t* kbase = qkv + ((size_t)b * LSEQ) * RS + HID + h * HD;
  const bf16_t* vtbase = vT + (size_t)bh * HD * LSEQ;

  // stage Q [128][64] via DMA, source-swizzled
#pragma unroll
  for (int s = 0; s < 4; ++s) {
    int l = t + s * 256;
    int r = l >> 3, c8 = l & 7;
    gld_lds16(qbase + (size_t)r * RS + ((c8 ^ (r & 7)) * 8), Qs + l * 8);
  }
  __syncthreads();

  // hoist Q B-frags (wave w owns q-tile 32w), pre-scaled
  const float sc = 0.18033688011112042f;  // (1/sqrt(64)) * log2(e)
  bf16x8 bq[4];
  {
    int qrow = 32 * w + l32;
#pragma unroll
    for (int c = 0; c < 4; ++c) {
      int y = 2 * c + hi;
      bf16x8 q8 = *(const bf16x8*)(Qs + qrow * 64 + ((y ^ (qrow & 7)) * 8));
#pragma unroll
      for (int e = 0; e < 8; ++e) q8[e] = (bf16_t)((float)q8[e] * sc);
      bq[c] = q8;
    }
  }

  // stage K/V tile kt into slot: Ks [128 k][64 d], Vts [64 d][128 j]
  auto stageKV = [&](int slot, int kt) {
    bf16_t* Ks = smem + slot * 16384;
    bf16_t* Vts = Ks + 8192;
#pragma unroll
    for (int s = 0; s < 4; ++s) {
      int l = t + s * 256;
      int r = l >> 3, c8 = l & 7;
      gld_lds16(kbase + (size_t)(kt * 128 + r) * RS + ((c8 ^ (r & 7)) * 8), Ks + l * 8);
      int rv = l >> 4, c16 = l & 15;
      gld_lds16(vtbase + (size_t)rv * LSEQ + kt * 128 + ((c16 ^ (rv & 7)) * 8), Vts + l * 8);
    }
  };

  f32x16 accO[2];
#pragma unroll
  for (int dt = 0; dt < 2; ++dt)
#pragma unroll
    for (int e = 0; e < 16; ++e) accO[dt][e] = 0.f;
  float l_acc = 0.f;

  constexpr int NT = LSEQ / 128;  // 16
  stageKV(0, 0);                  // 8 loads in flight

  for (int kt = 0; kt < NT; ++kt) {
    const int cs = kt & 1;
    if (kt + 1 < NT) {
      stageKV(1 - cs, kt + 1);    // issue next tile first (hides K/V latency)
      vmwait(8);                  // tile kt's 8 loads landed; kt+1's in flight
    } else {
      vmwait(0);
    }
    block_bar();                  // all waves' tile-kt loads visible
    const bf16_t* Ks = smem + cs * 16384;
    const bf16_t* Vts = Ks + 8192;

#pragma unroll
    for (int kt2 = 0; kt2 < 2; ++kt2) {
      // S^T for 2 k-tiles (rows 64*kt2 .. +64) x this wave's 32 q
      f32x16 s0, s1;
#pragma unroll
      for (int e = 0; e < 16; ++e) { s0[e] = 0.f; s1[e] = 0.f; }
      __builtin_amdgcn_s_setprio(1);
#pragma unroll
      for (int c = 0; c < 4; ++c) {
        int y = 2 * c + hi;
        int r0 = (2 * kt2 + 0) * 32 + l32;
        bf16x8 a0 = *(const bf16x8*)(Ks + r0 * 64 + ((y ^ (r0 & 7)) * 8));
        s0 = __builtin_amdgcn_mfma_f32_32x32x16_bf16(a0, bq[c], s0, 0, 0, 0);
        int r1 = (2 * kt2 + 1) * 32 + l32;
        bf16x8 a1 = *(const bf16x8*)(Ks + r1 * 64 + ((y ^ (r1 & 7)) * 8));
        s1 = __builtin_amdgcn_mfma_f32_32x32x16_bf16(a1, bq[c], s1, 0, 0, 0);
      }
      __builtin_amdgcn_s_setprio(0);

      // p = exp2(s); pack to bf16 pairs; assemble P^T B-frags via permlane swaps
      unsigned pf[2][2][4];  // [tile][c2][reg]
#pragma unroll
      for (int tile = 0; tile < 2; ++tile) {
        f32x16& sv = tile ? s1 : s0;
        float p[16];
#pragma unroll
        for (int e = 0; e < 16; ++e) { p[e] = EXP2F(sv[e]); l_acc += p[e]; }
        unsigned lo[4], hi_[4];
#pragma unroll
        for (int g = 0; g < 4; ++g) {
          lo[g] = pk_bf16(p[4 * g + 0], p[4 * g + 1]);
          hi_[g] = pk_bf16(p[4 * g + 2], p[4 * g + 3]);
        }
#pragma unroll
        for (int c2 = 0; c2 < 2; ++c2) {
          unsigned aL = lo[2 * c2], bL = lo[2 * c2 + 1];
          swap32(aL, bL);
          pf[tile][c2][0] = aL; pf[tile][c2][2] = bL;
          unsigned aH = hi_[2 * c2], bH = hi_[2 * c2 + 1];
          swap32(aH, bH);
          pf[tile][c2][1] = aH; pf[tile][c2][3] = bH;
        }
      }

      // O^T += V^T · P^T
      __builtin_amdgcn_s_setprio(1);
#pragma unroll
      for (int dt = 0; dt < 2; ++dt)
#pragma unroll
        for (int tile = 0; tile < 2; ++tile)
#pragma unroll
          for (int c2 = 0; c2 < 2; ++c2) {
            int ktile = 2 * kt2 + tile;
            int c8v = ktile * 4 + c2 * 2 + hi;
            int rv = dt * 32 + l32;
            bf16x8 av = *(const bf16x8*)(Vts + rv * 128 + ((c8v ^ (rv & 7)) * 8));
            union { unsigned u[4]; bf16x8 v; } bp;
            bp.u[0] = pf[tile][c2][0]; bp.u[1] = pf[tile][c2][1];
            bp.u[2] = pf[tile][c2][2]; bp.u[3] = pf[tile][c2][3];
            accO[dt] = __builtin_amdgcn_mfma_f32_32x32x16_bf16(av, bp.v, accO[dt], 0, 0, 0);
          }
      __builtin_amdgcn_s_setprio(0);
    }
    block_bar();  // reads of slot cs done -> next iter may stage into it
  }

  // denominator: col q = l32 per lane; halves hold partial sums
  l_acc += __shfl_xor(l_acc, 32, 64);
  float inv = 1.f / l_acc;

  // epilogue: O^T -> LDS (stride 68) -> coalesced global
  bf16_t* Osh = smem;
  {
    int q = 32 * w + l32;
#pragma unroll
    for (int dt = 0; dt < 2; ++dt)
#pragma unroll
      for (int e = 0; e < 16; ++e) {
        int d = dt * 32 + (e & 3) + 8 * (e >> 2) + 4 * hi;
        Osh[q * 68 + d] = (bf16_t)(accO[dt][e] * inv);
      }
  }
  __syncthreads();
#pragma unroll
  for (int s = 0; s < 4; ++s) {
    int l = t + s * 256;
    int r = l >> 3, c8 = l & 7;
    bf16x8 v = *(const bf16x8*)(Osh + r * 68 + c8 * 8);
    *(bf16x8*)(ob + ((size_t)(b * LSEQ + qt * 128 + r)) * HID + h * HD + c8 * 8) = v;
  }
}

// ---------------- residual add + LayerNorm ----------------
__global__ __launch_bounds__(256) void resid_ln(const float* __restrict__ X,
                                                const float* __restrict__ Y,
                                                const float* __restrict__ g,
                                                const float* __restrict__ be,
                                                float* __restrict__ outf,
                                                bf16_t* __restrict__ outb) {
  const int row = blockIdx.x;
  const int t = threadIdx.x;
  float4 a = ((const float4*)X)[(size_t)row * 256 + t];
  float4 bvec = ((const float4*)Y)[(size_t)row * 256 + t];
  float v0 = a.x + bvec.x, v1 = a.y + bvec.y, v2 = a.z + bvec.z, v3 = a.w + bvec.w;
  float s = v0 + v1 + v2 + v3;
  float s2 = v0 * v0 + v1 * v1 + v2 * v2 + v3 * v3;
#pragma unroll
  for (int msk = 1; msk < 64; msk <<= 1) {
    s += __shfl_xor(s, msk, 64);
    s2 += __shfl_xor(s2, msk, 64);
  }
  __shared__ float red[8];
  int w = t >> 6;
  if ((t & 63) == 0) { red[w] = s; red[w + 4] = s2; }
  __syncthreads();
  s = red[0] + red[1] + red[2] + red[3];
  s2 = red[4] + red[5] + red[6] + red[7];
  float mu = s * (1.f / 1024.f);
  float var = s2 * (1.f / 1024.f) - mu * mu;
  float rstd = rsqrtf(var + 1e-5f);
  float4 gg = ((const float4*)g)[t];
  float4 bb = ((const float4*)be)[t];
  float o0 = (v0 - mu) * rstd * gg.x + bb.x;
  float o1 = (v1 - mu) * rstd * gg.y + bb.y;
  float o2 = (v2 - mu) * rstd * gg.z + bb.z;
  float o3 = (v3 - mu) * rstd * gg.w + bb.w;
  float4 o = {o0, o1, o2, o3};
  ((float4*)outf)[(size_t)row * 256 + t] = o;
  if (outb) {
    bf16x4 ob4;
    ob4[0] = (bf16_t)o0; ob4[1] = (bf16_t)o1; ob4[2] = (bf16_t)o2; ob4[3] = (bf16_t)o3;
    ((bf16x4*)outb)[(size_t)row * 256 + t] = ob4;
  }
}

// ---------------- host ----------------
extern "C" void kernel_launch(void* const* d_in, const int* in_sizes, int n_in,
                              void* d_out, int out_size, void* d_ws, size_t ws_size,
                              hipStream_t stream) {
  const float* x     = (const float*)d_in[0];
  const float* Wqkv  = (const float*)d_in[1];
  const float* bqkv  = (const float*)d_in[2];
  const float* Wproj = (const float*)d_in[3];
  const float* bproj = (const float*)d_in[4];
  const float* W1    = (const float*)d_in[5];
  const float* b1    = (const float*)d_in[6];
  const float* W2    = (const float*)d_in[7];
  const float* b2    = (const float*)d_in[8];
  const float* g1    = (const float*)d_in[9];
  const float* be1   = (const float*)d_in[10];
  const float* g2    = (const float*)d_in[11];
  const float* be2   = (const float*)d_in[12];
  float* out = (float*)d_out;

  char* ws = (char*)d_ws;
  size_t off = 0;
  auto alloc = [&](size_t bytes) -> char* {
    char* p = ws + off;
    off += (bytes + 255) & ~(size_t)255;
    return p;
  };
  bf16_t* wqkvT  = (bf16_t*)alloc((size_t)3072 * 1024 * 2);
  bf16_t* wprojT = (bf16_t*)alloc((size_t)1024 * 1024 * 2);
  bf16_t* w1T    = (bf16_t*)alloc((size_t)4096 * 1024 * 2);
  bf16_t* w2T    = (bf16_t*)alloc((size_t)1024 * 4096 * 2);
  char*   xb_ob  = alloc((size_t)MROWS * HID * 2);
  char*   qkv_ff = alloc((size_t)MROWS * EXPD * 2);
  char*   a_f2   = alloc((size_t)MROWS * HID * 4);
  float*  h      = (float*)alloc((size_t)MROWS * HID * 4);
  bf16_t* hb     = (bf16_t*)alloc((size_t)MROWS * HID * 2);

  bf16_t* xb    = (bf16_t*)xb_ob;
  bf16_t* ob    = (bf16_t*)xb_ob;
  bf16_t* qkvb  = (bf16_t*)qkv_ff;
  bf16_t* ff1b  = (bf16_t*)qkv_ff;
  float*  attnf = (float*)a_f2;
  float*  ff2f  = (float*)a_f2;
  bf16_t* vTg   = hb;  // alias: vT live only qkv->attn; hb live only after LN1

  dim3 blk(256);
  dim3 blk512(512);
  transpose_cvt<<<dim3(3072 / 32, 1024 / 32), blk, 0, stream>>>(Wqkv, wqkvT, 1024, 3072);
  transpose_cvt<<<dim3(1024 / 32, 1024 / 32), blk, 0, stream>>>(Wproj, wprojT, 1024, 1024);
  transpose_cvt<<<dim3(4096 / 32, 1024 / 32), blk, 0, stream>>>(W1, w1T, 1024, 4096);
  transpose_cvt<<<dim3(1024 / 32, 4096 / 32), blk, 0, stream>>>(W2, w2T, 4096, 1024);
  cvt_bf16<<<MROWS * HID / 4 / 256, blk, 0, stream>>>(x, xb, MROWS * HID / 4);

  gemm_k<128, 256, 512><<<dim3(3072 / 256, MROWS / 128), blk512, 0, stream>>>(
      xb, wqkvT, bqkv, qkvb, MROWS, 3072, 1024, 0);
  transpose_v<<<dim3(LSEQ / 64, BATCH * NHEAD), blk, 0, stream>>>(qkvb, vTg);
  attn_kernel<<<dim3(LSEQ / 128, NHEAD, BATCH), blk, 0, stream>>>(qkvb, vTg, ob);
  gemm_k<128, 128, 256><<<dim3(1024 / 128, MROWS / 128), blk, 0, stream>>>(
      ob, wprojT, bproj, attnf, MROWS, 1024, 1024, 2);
  resid_ln<<<MROWS, blk, 0, stream>>>(x, attnf, g1, be1, h, hb);
  gemm_k<128, 256, 512><<<dim3(4096 / 256, MROWS / 128), blk512, 0, stream>>>(
      hb, w1T, b1, ff1b, MROWS, 4096, 1024, 1);
  gemm_k<128, 128, 256><<<dim3(1024 / 128, MROWS / 128), blk, 0, stream>>>(
      ff1b, w2T, b2, ff2f, MROWS, 1024, 4096, 2);
  resid_ln<<<MROWS, blk, 0, stream>>>(h, ff2f, g2, be2, out, (bf16_t*)nullptr);
}

// Round 5
// 550.479 us; speedup vs baseline: 1.1454x; 1.0338x over previous
//
#include <hip/hip_runtime.h>
#include <hip/hip_bf16.h>
#include <math.h>

// Transformer block, MI355X gfx950.
// R10: FF2 split-K x2 (z-grid), keeping per-wave 64x64 shape: 512 blocks of
//   8 waves -> 16 waves/CU (was 8). z=0 writes f2a(+bias), z=1 writes raw
//   f32 partial f2b; final resid_ln fuses LN(h + f2a + f2b). No extra
//   workspace: allocs reordered so dead-by-FF2 buffers (wqkvT|wprojT|w1T|
//   xb_ob = 32MB) host f2b.
// R9: attn K/V double-buffer + counted vmcnt(8), 80KB LDS, setprio on MFMA.
// R8: GEMM lean single-barrier counted-vmcnt loop, 3-slot LDS rotation:
//   QKV/FF1(/FF2): 128x256, 512thr, 72KB, 2 blocks/CU; proj: 128x128,
//   256thr, 48KB, up to 3 blocks/CU.

typedef __bf16 bf16_t;
typedef __bf16 bf16x8 __attribute__((ext_vector_type(8)));
typedef __bf16 bf16x4 __attribute__((ext_vector_type(4)));
typedef float f32x4 __attribute__((ext_vector_type(4)));
typedef float f32x16 __attribute__((ext_vector_type(16)));

#define HID   1024
#define NHEAD 16
#define HD    64
#define EXPD  4096
#define LSEQ  2048
#define BATCH 4
#define MROWS (BATCH * LSEQ)   // 8192

#if __has_builtin(__builtin_amdgcn_exp2f)
#define EXP2F __builtin_amdgcn_exp2f
#else
#define EXP2F exp2f
#endif

__device__ __forceinline__ void gld_lds16(const bf16_t* g, bf16_t* l) {
  __builtin_amdgcn_global_load_lds(
      (const __attribute__((address_space(1))) void*)g,
      (__attribute__((address_space(3))) void*)l, 16, 0, 0);
}

__device__ __forceinline__ void vmwait(int n) {
  // call sites pass constants; dead branches fold away
  if (n == 8)      asm volatile("s_waitcnt vmcnt(8)" ::: "memory");
  else if (n == 4) asm volatile("s_waitcnt vmcnt(4)" ::: "memory");
  else if (n == 3) asm volatile("s_waitcnt vmcnt(3)" ::: "memory");
  else if (n == 0) asm volatile("s_waitcnt vmcnt(0)" ::: "memory");
}

__device__ __forceinline__ void block_bar() {
  asm volatile("" ::: "memory");
  __builtin_amdgcn_s_barrier();
  asm volatile("" ::: "memory");
}

// a'[0:31]=a, a'[32:63]=b[0:31]; b'[0:31]=a[32:63], b'[32:63]=b
__device__ __forceinline__ void swap32(unsigned& a, unsigned& b) {
#if __has_builtin(__builtin_amdgcn_permlane32_swap)
  auto r = __builtin_amdgcn_permlane32_swap(a, b, false, false);
  a = r[0]; b = r[1];
#else
  bool hiL = ((threadIdx.x & 63) >= 32);
  unsigned pa = (unsigned)__shfl_xor((int)a, 32, 64);
  unsigned pb = (unsigned)__shfl_xor((int)b, 32, 64);
  unsigned na = hiL ? pb : a;
  unsigned nb = hiL ? b : pa;
  a = na; b = nb;
#endif
}

__device__ __forceinline__ unsigned pk_bf16(float lo, float hi) {
  bf16_t l = (bf16_t)lo, h = (bf16_t)hi;
  unsigned short ul, uh;
  __builtin_memcpy(&ul, &l, 2);
  __builtin_memcpy(&uh, &h, 2);
  return (unsigned)ul | ((unsigned)uh << 16);
}

// ---------------- convert f32 -> bf16 (x) ----------------
__global__ __launch_bounds__(256) void cvt_bf16(const float* __restrict__ in,
                                                bf16_t* __restrict__ out, int n4) {
  int i = blockIdx.x * 256 + threadIdx.x;
  if (i >= n4) return;
  float4 v = ((const float4*)in)[i];
  bf16x4 o;
  o[0] = (bf16_t)v.x; o[1] = (bf16_t)v.y; o[2] = (bf16_t)v.z; o[3] = (bf16_t)v.w;
  ((bf16x4*)out)[i] = o;
}

// ---------------- transpose + convert: W[K][N] f32 -> Wt[N][K] bf16 ----------------
__global__ __launch_bounds__(256) void transpose_cvt(const float* __restrict__ W,
                                                     bf16_t* __restrict__ Wt,
                                                     int K, int N) {
  __shared__ float tile[32][33];
  int n0 = blockIdx.x * 32, k0 = blockIdx.y * 32;
  int tx = threadIdx.x & 31, ty = threadIdx.x >> 5;
#pragma unroll
  for (int i = 0; i < 32; i += 8)
    tile[ty + i][tx] = W[(size_t)(k0 + ty + i) * N + n0 + tx];
  __syncthreads();
#pragma unroll
  for (int i = 0; i < 32; i += 8)
    Wt[(size_t)(n0 + ty + i) * K + k0 + tx] = (bf16_t)tile[tx][ty + i];
}

// ---------------- transpose V: qkvb V-part -> vT[b*16+h][d][l] bf16 ----------------
__global__ __launch_bounds__(256) void transpose_v(const bf16_t* __restrict__ qkvb,
                                                   bf16_t* __restrict__ vT) {
  __shared__ bf16_t tile[64][65];
  const int l0 = blockIdx.x * 64;
  const int bh = blockIdx.y;
  const int b = bh >> 4, h = bh & 15;
  const int tx = threadIdx.x & 63, ty = threadIdx.x >> 6;
  const bf16_t* src = qkvb + ((size_t)(b * LSEQ + l0)) * 3072 + 2048 + h * 64;
#pragma unroll
  for (int i = 0; i < 16; ++i) {
    int l = ty + 4 * i;
    tile[l][tx] = src[(size_t)l * 3072 + tx];
  }
  __syncthreads();
  bf16_t* dst = vT + ((size_t)bh * HD) * LSEQ + l0;
#pragma unroll
  for (int i = 0; i < 16; ++i) {
    int d = ty + 4 * i;
    dst[(size_t)d * LSEQ + tx] = tile[tx][d];
  }
}

// ---------------- GEMM: C[M][N] = A[M][K] @ Bt[N][K]^T + bias ----------------
// mode 0: bf16 out; mode 1: gelu(tanh) then bf16 out; mode 2: f32 out.
// Split-K: launch with gridDim.z = Z; part z covers K-range [z*K/Z, ...).
//   z == 0 writes C (+bias, +activation per mode); z > 0 writes raw f32
//   partial to C2 (consumer must sum). Row stride stays K.
// BM x BN tile, NTHR threads, per-wave output 64x64:
//   16 MFMA + 8 ds_read_b128 per K-step.
// 3-slot LDS rotation, 2-deep prefetch, 1 barrier + 1 counted vmcnt / K-step.
template <int BM, int BN, int NTHR>
__global__ __launch_bounds__(NTHR, (NTHR == 512 ? 4 : 3))
void gemm_k(const bf16_t* __restrict__ A,
            const bf16_t* __restrict__ Bt,
            const float* __restrict__ bias,
            void* __restrict__ C,
            float* __restrict__ C2,
            int M, int N, int K, int mode) {
  constexpr int WC = (NTHR / 64) / 2;        // wave-grid cols (4 or 2)
  constexpr int AL = BM * 4 / NTHR;          // A gld_lds per thread (1 or 2)
  constexpr int BL = BN * 4 / NTHR;          // B gld_lds per thread (2)
  constexpr int LOADS = AL + BL;             // 3 or 4
  constexpr int RSTEP = NTHR >> 2;           // rows covered per load pass
  __shared__ bf16_t As[3 * BM * 32];
  __shared__ bf16_t Bs[3 * BN * 32];

  // group-M block swizzle: same-XCD blocks (ids = c mod 8) share an A-strip
  const int nbx = gridDim.x;
  int p = blockIdx.y * nbx + blockIdx.x;
  const int GM = 8;
  int group = p / (GM * nbx);
  int idx = p - group * (GM * nbx);
  const int by = group * GM + (idx & (GM - 1));
  const int bx = idx >> 3;  // GM == 8
  const int n0 = bx * BN, m0 = by * BM;

  const int zz = blockIdx.z;
  const int kLen = K / (int)gridDim.z;
  const int kOff = zz * kLen;

  const int t = threadIdx.x;
  const int lane = t & 63, w = t >> 6;
  const int wr = w / WC, wc = w % WC;
  const int quad = lane >> 4, l16 = lane & 15;

  f32x4 acc[4][4];
#pragma unroll
  for (int i = 0; i < 4; ++i)
#pragma unroll
    for (int j = 0; j < 4; ++j) acc[i][j] = (f32x4){0.f, 0.f, 0.f, 0.f};

  // loop-invariant per-lane DMA source offsets (chunk-XOR swizzled k-chunk)
  const int r0 = t >> 2;
  const unsigned ksw = (((unsigned)t & 3u) ^ ((unsigned)(r0 >> 1) & 3u)) * 8u;
  const unsigned offR0 = (unsigned)r0 * (unsigned)K + ksw;
  // row steps of RSTEP (64/128) preserve (r>>1)&3 -> same swizzle

  const bf16_t* aB = A + (size_t)m0 * K + kOff;
  const bf16_t* bB = Bt + (size_t)n0 * K + kOff;

  // loop-invariant LDS frag read offsets (elems); chunk = quad ^ ((row>>1)&3)
  unsigned aoff[4], boff[4];
#pragma unroll
  for (int i = 0; i < 4; ++i) {
    int row = wr * 64 + 16 * i + l16;
    aoff[i] = (unsigned)(row * 32 + (quad ^ ((row >> 1) & 3)) * 8);
  }
#pragma unroll
  for (int j = 0; j < 4; ++j) {
    int row = wc * 64 + 16 * j + l16;
    boff[j] = (unsigned)(row * 32 + (quad ^ ((row >> 1) & 3)) * 8);
  }

  auto stage = [&](int slot, int kk) {
    bf16_t* Asl = As + slot * (BM * 32);
    bf16_t* Bsl = Bs + slot * (BN * 32);
    const bf16_t* aS = aB + kk;
    const bf16_t* bS = bB + kk;
#pragma unroll
    for (int a = 0; a < AL; ++a)
      gld_lds16(aS + offR0 + (size_t)a * RSTEP * K, Asl + (t + a * NTHR) * 8);
#pragma unroll
    for (int b = 0; b < BL; ++b)
      gld_lds16(bS + offR0 + (size_t)b * RSTEP * K, Bsl + (t + b * NTHR) * 8);
  };

  const int NT = kLen >> 5;   // kLen/32 tiles; NT >= 3 required

  // prologue: stage tiles 0,1; wait tile 0
  stage(0, 0);
  stage(1, 32);
  vmwait(LOADS);
  block_bar();

  int cs = 0;  // LDS slot holding tile kt
  for (int kt = 0; kt < NT; ++kt) {
    if (kt < NT - 2) {
      int ss = cs == 0 ? 2 : cs - 1;   // (cs+2)%3 — freed by last barrier
      stage(ss, (kt + 2) * 32);
    }
    const bf16_t* Asl = As + cs * (BM * 32);
    const bf16_t* Bsl = Bs + cs * (BN * 32);
    bf16x8 af[4], bfr[4];
#pragma unroll
    for (int i = 0; i < 4; ++i) af[i] = *(const bf16x8*)(Asl + aoff[i]);
#pragma unroll
    for (int j = 0; j < 4; ++j) bfr[j] = *(const bf16x8*)(Bsl + boff[j]);
    __builtin_amdgcn_s_setprio(1);
#pragma unroll
    for (int i = 0; i < 4; ++i)
#pragma unroll
      for (int j = 0; j < 4; ++j)
        acc[i][j] = __builtin_amdgcn_mfma_f32_16x16x32_bf16(af[i], bfr[j], acc[i][j], 0, 0, 0);
    __builtin_amdgcn_s_setprio(0);
    if (kt < NT - 2)      vmwait(LOADS);  // tile kt+1 landed (kt+2 in flight)
    else if (kt == NT - 2) vmwait(0);     // tile NT-1 landed
    if (kt < NT - 1) block_bar();
    cs = cs == 2 ? 0 : cs + 1;
  }

#pragma unroll
  for (int i = 0; i < 4; ++i) {
    int rowb = m0 + wr * 64 + 16 * i + quad * 4;
#pragma unroll
    for (int j = 0; j < 4; ++j) {
      int col = n0 + wc * 64 + 16 * j + l16;
      float bv = (zz == 0) ? bias[col] : 0.f;
#pragma unroll
      for (int r = 0; r < 4; ++r) {
        float v = acc[i][j][r] + bv;
        size_t idx = (size_t)(rowb + r) * N + col;
        if (zz != 0) {
          C2[idx] = v;  // raw f32 partial; consumer sums
        } else if (mode == 0) {
          ((bf16_t*)C)[idx] = (bf16_t)v;
        } else if (mode == 1) {
          // tanh-approx gelu (max |err| ~3e-4, threshold 0.109)
          float u = v * (0.7978845608028654f + 0.0356774081f * v * v);
          float e = EXP2F(u * 2.885390082f);  // exp(2u) = 2^(2u*log2e)
          float th = (e - 1.f) / (e + 1.f);
          float gel = 0.5f * v * (1.f + th);
          ((bf16_t*)C)[idx] = (bf16_t)gel;
        } else {
          ((float*)C)[idx] = v;
        }
      }
    }
  }
}

// ---------------- flash attention: 128q/block, operand-swapped, reg-resident P ----------------
// S^T[k][q] = K·(sc·Q)^T  (A=K, B=Q) ; O^T[d][q] = V^T · P^T  (A=V^T, B=P^T in regs)
// R9: K/V double-buffered (2 slots) + counted vmcnt(8); 80 KB LDS, 2 blocks/CU.
__global__ __launch_bounds__(256, 2) void attn_kernel(const bf16_t* __restrict__ qkv,
                                                      const bf16_t* __restrict__ vT,
                                                      bf16_t* __restrict__ ob) {
  __shared__ bf16_t smem[5 * 128 * 64];   // 80 KB: [Ks|Vts] x2 slots | Qs
  bf16_t* Qs = smem + 32768;    // [128 q][64 d]  unpadded, chunk-XOR swizzle
  const int qt = blockIdx.x, h = blockIdx.y, b = blockIdx.z;
  const int t = threadIdx.x, lane = t & 63, w = t >> 6;
  const int l32 = lane & 31, hi = lane >> 5;
  const size_t RS = 3 * HID;
  const int bh = b * NHEAD + h;

  const bf16_t* qbase = qkv + ((size_t)(b * LSEQ + qt * 128)) * RS + h * HD;
  const bf16_t* kbase = qkv + ((size_t)b * LSEQ) * RS + HID + h * HD;
  const bf16_t* vtbase = vT + (size_t)bh * HD * LSEQ;

  // stage Q [128][64] via DMA, source-swizzled
#pragma unroll
  for (int s = 0; s < 4; ++s) {
    int l = t + s * 256;
    int r = l >> 3, c8 = l & 7;
    gld_lds16(qbase + (size_t)r * RS + ((c8 ^ (r & 7)) * 8), Qs + l * 8);
  }
  __syncthreads();

  // hoist Q B-frags (wave w owns q-tile 32w), pre-scaled
  const float sc = 0.18033688011112042f;  // (1/sqrt(64)) * log2(e)
  bf16x8 bq[4];
  {
    int qrow = 32 * w + l32;
#pragma unroll
    for (int c = 0; c < 4; ++c) {
      int y = 2 * c + hi;
      bf16x8 q8 = *(const bf16x8*)(Qs + qrow * 64 + ((y ^ (qrow & 7)) * 8));
#pragma unroll
      for (int e = 0; e < 8; ++e) q8[e] = (bf16_t)((float)q8[e] * sc);
      bq[c] = q8;
    }
  }

  // stage K/V tile kt into slot: Ks [128 k][64 d], Vts [64 d][128 j]
  auto stageKV = [&](int slot, int kt) {
    bf16_t* Ks = smem + slot * 16384;
    bf16_t* Vts = Ks + 8192;
#pragma unroll
    for (int s = 0; s < 4; ++s) {
      int l = t + s * 256;
      int r = l >> 3, c8 = l & 7;
      gld_lds16(kbase + (size_t)(kt * 128 + r) * RS + ((c8 ^ (r & 7)) * 8), Ks + l * 8);
      int rv = l >> 4, c16 = l & 15;
      gld_lds16(vtbase + (size_t)rv * LSEQ + kt * 128 + ((c16 ^ (rv & 7)) * 8), Vts + l * 8);
    }
  };

  f32x16 accO[2];
#pragma unroll
  for (int dt = 0; dt < 2; ++dt)
#pragma unroll
    for (int e = 0; e < 16; ++e) accO[dt][e] = 0.f;
  float l_acc = 0.f;

  constexpr int NT = LSEQ / 128;  // 16
  stageKV(0, 0);                  // 8 loads in flight

  for (int kt = 0; kt < NT; ++kt) {
    const int cs = kt & 1;
    if (kt + 1 < NT) {
      stageKV(1 - cs, kt + 1);    // issue next tile first (hides K/V latency)
      vmwait(8);                  // tile kt's 8 loads landed; kt+1's in flight
    } else {
      vmwait(0);
    }
    block_bar();                  // all waves' tile-kt loads visible
    const bf16_t* Ks = smem + cs * 16384;
    const bf16_t* Vts = Ks + 8192;

#pragma unroll
    for (int kt2 = 0; kt2 < 2; ++kt2) {
      // S^T for 2 k-tiles (rows 64*kt2 .. +64) x this wave's 32 q
      f32x16 s0, s1;
#pragma unroll
      for (int e = 0; e < 16; ++e) { s0[e] = 0.f; s1[e] = 0.f; }
      __builtin_amdgcn_s_setprio(1);
#pragma unroll
      for (int c = 0; c < 4; ++c) {
        int y = 2 * c + hi;
        int r0 = (2 * kt2 + 0) * 32 + l32;
        bf16x8 a0 = *(const bf16x8*)(Ks + r0 * 64 + ((y ^ (r0 & 7)) * 8));
        s0 = __builtin_amdgcn_mfma_f32_32x32x16_bf16(a0, bq[c], s0, 0, 0, 0);
        int r1 = (2 * kt2 + 1) * 32 + l32;
        bf16x8 a1 = *(const bf16x8*)(Ks + r1 * 64 + ((y ^ (r1 & 7)) * 8));
        s1 = __builtin_amdgcn_mfma_f32_32x32x16_bf16(a1, bq[c], s1, 0, 0, 0);
      }
      __builtin_amdgcn_s_setprio(0);

      // p = exp2(s); pack to bf16 pairs; assemble P^T B-frags via permlane swaps
      unsigned pf[2][2][4];  // [tile][c2][reg]
#pragma unroll
      for (int tile = 0; tile < 2; ++tile) {
        f32x16& sv = tile ? s1 : s0;
        float p[16];
#pragma unroll
        for (int e = 0; e < 16; ++e) { p[e] = EXP2F(sv[e]); l_acc += p[e]; }
        unsigned lo[4], hi_[4];
#pragma unroll
        for (int g = 0; g < 4; ++g) {
          lo[g] = pk_bf16(p[4 * g + 0], p[4 * g + 1]);
          hi_[g] = pk_bf16(p[4 * g + 2], p[4 * g + 3]);
        }
#pragma unroll
        for (int c2 = 0; c2 < 2; ++c2) {
          unsigned aL = lo[2 * c2], bL = lo[2 * c2 + 1];
          swap32(aL, bL);
          pf[tile][c2][0] = aL; pf[tile][c2][2] = bL;
          unsigned aH = hi_[2 * c2], bH = hi_[2 * c2 + 1];
          swap32(aH, bH);
          pf[tile][c2][1] = aH; pf[tile][c2][3] = bH;
        }
      }

      // O^T += V^T · P^T
      __builtin_amdgcn_s_setprio(1);
#pragma unroll
      for (int dt = 0; dt < 2; ++dt)
#pragma unroll
        for (int tile = 0; tile < 2; ++tile)
#pragma unroll
          for (int c2 = 0; c2 < 2; ++c2) {
            int ktile = 2 * kt2 + tile;
            int c8v = ktile * 4 + c2 * 2 + hi;
            int rv = dt * 32 + l32;
            bf16x8 av = *(const bf16x8*)(Vts + rv * 128 + ((c8v ^ (rv & 7)) * 8));
            union { unsigned u[4]; bf16x8 v; } bp;
            bp.u[0] = pf[tile][c2][0]; bp.u[1] = pf[tile][c2][1];
            bp.u[2] = pf[tile][c2][2]; bp.u[3] = pf[tile][c2][3];
            accO[dt] = __builtin_amdgcn_mfma_f32_32x32x16_bf16(av, bp.v, accO[dt], 0, 0, 0);
          }
      __builtin_amdgcn_s_setprio(0);
    }
    block_bar();  // reads of slot cs done -> next iter may stage into it
  }

  // denominator: col q = l32 per lane; halves hold partial sums
  l_acc += __shfl_xor(l_acc, 32, 64);
  float inv = 1.f / l_acc;

  // epilogue: O^T -> LDS (stride 68) -> coalesced global
  bf16_t* Osh = smem;
  {
    int q = 32 * w + l32;
#pragma unroll
    for (int dt = 0; dt < 2; ++dt)
#pragma unroll
      for (int e = 0; e < 16; ++e) {
        int d = dt * 32 + (e & 3) + 8 * (e >> 2) + 4 * hi;
        Osh[q * 68 + d] = (bf16_t)(accO[dt][e] * inv);
      }
  }
  __syncthreads();
#pragma unroll
  for (int s = 0; s < 4; ++s) {
    int l = t + s * 256;
    int r = l >> 3, c8 = l & 7;
    bf16x8 v = *(const bf16x8*)(Osh + r * 68 + c8 * 8);
    *(bf16x8*)(ob + ((size_t)(b * LSEQ + qt * 128 + r)) * HID + h * HD + c8 * 8) = v;
  }
}

// ---------------- residual add (2 or 3 way) + LayerNorm ----------------
__global__ __launch_bounds__(256) void resid_ln(const float* __restrict__ X,
                                                const float* __restrict__ Y,
                                                const float* __restrict__ Y2,
                                                const float* __restrict__ g,
                                                const float* __restrict__ be,
                                                float* __restrict__ outf,
                                                bf16_t* __restrict__ outb) {
  const int row = blockIdx.x;
  const int t = threadIdx.x;
  float4 a = ((const float4*)X)[(size_t)row * 256 + t];
  float4 bvec = ((const float4*)Y)[(size_t)row * 256 + t];
  float4 cvec = {0.f, 0.f, 0.f, 0.f};
  if (Y2) cvec = ((const float4*)Y2)[(size_t)row * 256 + t];
  float v0 = a.x + bvec.x + cvec.x, v1 = a.y + bvec.y + cvec.y;
  float v2 = a.z + bvec.z + cvec.z, v3 = a.w + bvec.w + cvec.w;
  float s = v0 + v1 + v2 + v3;
  float s2 = v0 * v0 + v1 * v1 + v2 * v2 + v3 * v3;
#pragma unroll
  for (int msk = 1; msk < 64; msk <<= 1) {
    s += __shfl_xor(s, msk, 64);
    s2 += __shfl_xor(s2, msk, 64);
  }
  __shared__ float red[8];
  int w = t >> 6;
  if ((t & 63) == 0) { red[w] = s; red[w + 4] = s2; }
  __syncthreads();
  s = red[0] + red[1] + red[2] + red[3];
  s2 = red[4] + red[5] + red[6] + red[7];
  float mu = s * (1.f / 1024.f);
  float var = s2 * (1.f / 1024.f) - mu * mu;
  float rstd = rsqrtf(var + 1e-5f);
  float4 gg = ((const float4*)g)[t];
  float4 bb = ((const float4*)be)[t];
  float o0 = (v0 - mu) * rstd * gg.x + bb.x;
  float o1 = (v1 - mu) * rstd * gg.y + bb.y;
  float o2 = (v2 - mu) * rstd * gg.z + bb.z;
  float o3 = (v3 - mu) * rstd * gg.w + bb.w;
  float4 o = {o0, o1, o2, o3};
  ((float4*)outf)[(size_t)row * 256 + t] = o;
  if (outb) {
    bf16x4 ob4;
    ob4[0] = (bf16_t)o0; ob4[1] = (bf16_t)o1; ob4[2] = (bf16_t)o2; ob4[3] = (bf16_t)o3;
    ((bf16x4*)outb)[(size_t)row * 256 + t] = ob4;
  }
}

// ---------------- host ----------------
extern "C" void kernel_launch(void* const* d_in, const int* in_sizes, int n_in,
                              void* d_out, int out_size, void* d_ws, size_t ws_size,
                              hipStream_t stream) {
  const float* x     = (const float*)d_in[0];
  const float* Wqkv  = (const float*)d_in[1];
  const float* bqkv  = (const float*)d_in[2];
  const float* Wproj = (const float*)d_in[3];
  const float* bproj = (const float*)d_in[4];
  const float* W1    = (const float*)d_in[5];
  const float* b1    = (const float*)d_in[6];
  const float* W2    = (const float*)d_in[7];
  const float* b2    = (const float*)d_in[8];
  const float* g1    = (const float*)d_in[9];
  const float* be1   = (const float*)d_in[10];
  const float* g2    = (const float*)d_in[11];
  const float* be2   = (const float*)d_in[12];
  float* out = (float*)d_out;

  // Workspace layout (184 MB total, alias-planned):
  //   [0,8M)    w2T          (setup -> FF2)
  //   [8,40M)   h            (LN1 -> LN2)
  //   [40,72M)  a_f2         (proj out -> LN1; FF2 z0 -> LN2)
  //   [72,136M) qkv_ff       (qkvb: QKV -> attn; ff1b: FF1 -> FF2)
  //   [136,184M) E:
  //     E+0:  wqkvT 6M  (setup -> QKV)      \
  //     E+6M: wprojT 2M (setup -> proj)      > f2b (FF2 z1 partial, 32M)
  //     E+8M: w1T 8M    (setup -> FF1)       > overlays these after FF1
  //     E+16M: xb_ob 16M (xb -> QKV; ob -> proj)
  //     E+32M: hb/vTg 16M (vTg -> attn; hb: LN1 -> FF1)
  char* ws = (char*)d_ws;
  bf16_t* w2T    = (bf16_t*)(ws);
  float*  h      = (float*) (ws + ((size_t)8 << 20));
  float*  a_f2   = (float*) (ws + ((size_t)40 << 20));
  bf16_t* qkv_ff = (bf16_t*)(ws + ((size_t)72 << 20));
  char*   E      = ws + ((size_t)136 << 20);
  bf16_t* wqkvT  = (bf16_t*)(E);
  bf16_t* wprojT = (bf16_t*)(E + ((size_t)6 << 20));
  bf16_t* w1T    = (bf16_t*)(E + ((size_t)8 << 20));
  char*   xb_ob  = E + ((size_t)16 << 20);
  bf16_t* hb     = (bf16_t*)(E + ((size_t)32 << 20));
  float*  f2b    = (float*)E;   // FF2 z1 partial: overlays wqkvT..xb_ob (dead)

  bf16_t* xb    = (bf16_t*)xb_ob;
  bf16_t* ob    = (bf16_t*)xb_ob;
  bf16_t* qkvb  = qkv_ff;
  bf16_t* ff1b  = qkv_ff;
  float*  attnf = a_f2;
  float*  ff2f  = a_f2;
  bf16_t* vTg   = hb;  // alias: vT live only qkv->attn; hb live only after LN1

  dim3 blk(256);
  dim3 blk512(512);
  transpose_cvt<<<dim3(3072 / 32, 1024 / 32), blk, 0, stream>>>(Wqkv, wqkvT, 1024, 3072);
  transpose_cvt<<<dim3(1024 / 32, 1024 / 32), blk, 0, stream>>>(Wproj, wprojT, 1024, 1024);
  transpose_cvt<<<dim3(4096 / 32, 1024 / 32), blk, 0, stream>>>(W1, w1T, 1024, 4096);
  transpose_cvt<<<dim3(1024 / 32, 4096 / 32), blk, 0, stream>>>(W2, w2T, 4096, 1024);
  cvt_bf16<<<MROWS * HID / 4 / 256, blk, 0, stream>>>(x, xb, MROWS * HID / 4);

  gemm_k<128, 256, 512><<<dim3(3072 / 256, MROWS / 128), blk512, 0, stream>>>(
      xb, wqkvT, bqkv, qkvb, nullptr, MROWS, 3072, 1024, 0);
  transpose_v<<<dim3(LSEQ / 64, BATCH * NHEAD), blk, 0, stream>>>(qkvb, vTg);
  attn_kernel<<<dim3(LSEQ / 128, NHEAD, BATCH), blk, 0, stream>>>(qkvb, vTg, ob);
  gemm_k<128, 128, 256><<<dim3(1024 / 128, MROWS / 128), blk, 0, stream>>>(
      ob, wprojT, bproj, attnf, nullptr, MROWS, 1024, 1024, 2);
  resid_ln<<<MROWS, blk, 0, stream>>>(x, attnf, nullptr, g1, be1, h, hb);
  gemm_k<128, 256, 512><<<dim3(4096 / 256, MROWS / 128), blk512, 0, stream>>>(
      hb, w1T, b1, ff1b, nullptr, MROWS, 4096, 1024, 1);
  // FF2 split-K x2: z0 -> ff2f (+bias), z1 -> f2b (raw partial)
  gemm_k<128, 256, 512><<<dim3(1024 / 256, MROWS / 128, 2), blk512, 0, stream>>>(
      ff1b, w2T, b2, ff2f, f2b, MROWS, 1024, 4096, 2);
  resid_ln<<<MROWS, blk, 0, stream>>>(h, ff2f, f2b, g2, be2, out, (bf16_t*)nullptr);
}